// Round 1
// baseline (7178.854 us; speedup 1.0000x reference)
//
#include <hip/hip_runtime.h>
#include <math.h>

#define N_NODES 50000
#define N_EDGES 800000
#define ET (N_EDGES + N_NODES)
#define N_GRAPHS 200
#define F_INN 16
#define C_DIM 64
#define N_HEADS 4
#define HIDD 256

// ---- order-preserving float<->uint encoding for atomicMax-based segment max.
// memset(0) == smaller than any encoded real float (== -inf init).
__device__ __forceinline__ unsigned fenc(float f) {
  unsigned u = __float_as_uint(f);
  return (u & 0x80000000u) ? ~u : (u | 0x80000000u);
}
__device__ __forceinline__ float fdec(unsigned u) {
  return (u & 0x80000000u) ? __uint_as_float(u & 0x7fffffffu) : __uint_as_float(~u);
}

// ---------------- dual GEMM: Cl = A@Bl, Cr = A@Br  (A: nrows x K, B: K x M)
template<int K, int M>
__global__ __launch_bounds__(256) void gemm_dual(
    const float* __restrict__ A, const float* __restrict__ Bl,
    const float* __restrict__ Br, float* __restrict__ Cl,
    float* __restrict__ Cr, int nrows)
{
  __shared__ __align__(16) float As[16][64];
  __shared__ __align__(16) float Bls[16][64];
  __shared__ __align__(16) float Brs[16][64];
  int tid = threadIdx.x;
  int row0 = blockIdx.x * 64;
  int col0 = blockIdx.y * 64;
  int tr = (tid >> 4) << 2;
  int tc = (tid & 15) << 2;
  float accL[4][4] = {{0.f}}, accR[4][4] = {{0.f}};
  int arow = tid >> 2, ak = (tid & 3) << 2;
  int brow = tid >> 4, bcol = (tid & 15) << 2;
  for (int k0 = 0; k0 < K; k0 += 16) {
    float4 av = make_float4(0.f, 0.f, 0.f, 0.f);
    int gr = row0 + arow;
    if (gr < nrows) av = *(const float4*)&A[(size_t)gr * K + k0 + ak];
    As[ak + 0][arow] = av.x;
    As[ak + 1][arow] = av.y;
    As[ak + 2][arow] = av.z;
    As[ak + 3][arow] = av.w;
    *(float4*)&Bls[brow][bcol] = *(const float4*)&Bl[(size_t)(k0 + brow) * M + col0 + bcol];
    *(float4*)&Brs[brow][bcol] = *(const float4*)&Br[(size_t)(k0 + brow) * M + col0 + bcol];
    __syncthreads();
    #pragma unroll
    for (int k = 0; k < 16; ++k) {
      float4 a = *(const float4*)&As[k][tr];
      float4 bl = *(const float4*)&Bls[k][tc];
      float4 br = *(const float4*)&Brs[k][tc];
      float aa[4] = {a.x, a.y, a.z, a.w};
      float lb[4] = {bl.x, bl.y, bl.z, bl.w};
      float rb[4] = {br.x, br.y, br.z, br.w};
      #pragma unroll
      for (int ii = 0; ii < 4; ++ii)
        #pragma unroll
        for (int jj = 0; jj < 4; ++jj) {
          accL[ii][jj] = fmaf(aa[ii], lb[jj], accL[ii][jj]);
          accR[ii][jj] = fmaf(aa[ii], rb[jj], accR[ii][jj]);
        }
    }
    __syncthreads();
  }
  #pragma unroll
  for (int ii = 0; ii < 4; ++ii) {
    int gr = row0 + tr + ii;
    if (gr < nrows) {
      *(float4*)&Cl[(size_t)gr * M + col0 + tc] =
          make_float4(accL[ii][0], accL[ii][1], accL[ii][2], accL[ii][3]);
      *(float4*)&Cr[(size_t)gr * M + col0 + tc] =
          make_float4(accR[ii][0], accR[ii][1], accR[ii][2], accR[ii][3]);
    }
  }
}

// ---------------- edge pass 1: e[edge,h] = att_h . leaky_relu(xl[src]+xr[dst]); segment max
template<int HEADS_, int D_>
__global__ __launch_bounds__(256) void edge_score(
    const float* __restrict__ xl, const float* __restrict__ xr,
    const float* __restrict__ att, const int* __restrict__ srcs,
    const int* __restrict__ dsts, float* __restrict__ ebuf,
    unsigned* __restrict__ menc)
{
  constexpr int GL = 64 / HEADS_;  // lanes per head group
  int i = blockIdx.x * 4 + (threadIdx.x >> 6);
  if (i >= ET) return;
  int lane = threadIdx.x & 63;
  int s, d;
  if (i < N_EDGES) { s = srcs[i]; d = dsts[i]; } else { s = d = i - N_EDGES; }
  float acc = 0.f;
  if constexpr (D_ == 256) {
    float4 a = *(const float4*)&xl[(size_t)s * D_ + lane * 4];
    float4 b = *(const float4*)&xr[(size_t)d * D_ + lane * 4];
    float4 w = *(const float4*)&att[lane * 4];
    float va[4] = {a.x + b.x, a.y + b.y, a.z + b.z, a.w + b.w};
    float ww[4] = {w.x, w.y, w.z, w.w};
    #pragma unroll
    for (int j = 0; j < 4; ++j) {
      float v = va[j];
      v = v > 0.f ? v : 0.2f * v;
      acc = fmaf(v, ww[j], acc);
    }
  } else {
    float v = xl[(size_t)s * D_ + lane] + xr[(size_t)d * D_ + lane];
    v = v > 0.f ? v : 0.2f * v;
    acc = v * att[lane];
  }
  for (int off = GL / 2; off > 0; off >>= 1) acc += __shfl_xor(acc, off);
  if ((lane & (GL - 1)) == 0) {
    int h = lane / GL;
    ebuf[(size_t)i * HEADS_ + h] = acc;
    atomicMax(&menc[d * HEADS_ + h], fenc(acc));
  }
}

// ---------------- edge pass 2: p = exp(e - m[dst]); denom[dst] += p
template<int HEADS_>
__global__ void edge_p(const int* __restrict__ dsts, float* __restrict__ ebuf,
                       const unsigned* __restrict__ menc, float* __restrict__ denom)
{
  int idx = blockIdx.x * blockDim.x + threadIdx.x;
  if (idx >= ET * HEADS_) return;
  int i = idx / HEADS_;
  int h = idx - i * HEADS_;
  int d = (i < N_EDGES) ? dsts[i] : i - N_EDGES;
  float m = fdec(menc[d * HEADS_ + h]);
  float p = __expf(ebuf[idx] - m);
  ebuf[idx] = p;
  atomicAdd(&denom[d * HEADS_ + h], p);
}

// ---------------- edge pass 3: out[dst] += (p/denom[dst]) * xl[src]
template<int HEADS_, int D_>
__global__ __launch_bounds__(256) void edge_accum(
    const float* __restrict__ xl, const float* __restrict__ ebuf,
    const float* __restrict__ denom, const int* __restrict__ srcs,
    const int* __restrict__ dsts, float* __restrict__ out)
{
  constexpr int GL = 64 / HEADS_;
  int i = blockIdx.x * 4 + (threadIdx.x >> 6);
  if (i >= ET) return;
  int lane = threadIdx.x & 63;
  int s, d;
  if (i < N_EDGES) { s = srcs[i]; d = dsts[i]; } else { s = d = i - N_EDGES; }
  int h = lane / GL;
  float p = ebuf[(size_t)i * HEADS_ + h];
  float alpha = p / (denom[d * HEADS_ + h] + 1e-16f);
  if constexpr (D_ == 256) {
    float4 a = *(const float4*)&xl[(size_t)s * D_ + lane * 4];
    float* o = &out[(size_t)d * D_ + lane * 4];
    atomicAdd(o + 0, alpha * a.x);
    atomicAdd(o + 1, alpha * a.y);
    atomicAdd(o + 2, alpha * a.z);
    atomicAdd(o + 3, alpha * a.w);
  } else {
    atomicAdd(&out[(size_t)d * D_ + lane], alpha * xl[(size_t)s * D_ + lane]);
  }
}

// ---------------- BN statistics (per-channel sum / sumsq)
template<int D_, int RPB>
__global__ __launch_bounds__(256) void bn_stats(const float* __restrict__ h,
    float* __restrict__ gsum, float* __restrict__ gsumsq, int nrows)
{
  constexpr int RG = 256 / D_;
  int c = threadIdx.x % D_;
  int rg = threadIdx.x / D_;
  int r0 = blockIdx.x * RPB;
  float s = 0.f, sq = 0.f;
  int rend = min(r0 + RPB, nrows);
  for (int r = r0 + rg; r < rend; r += RG) {
    float v = h[(size_t)r * D_ + c];
    s += v;
    sq = fmaf(v, v, sq);
  }
  atomicAdd(&gsum[c], s);
  atomicAdd(&gsumsq[c], sq);
}

__global__ void bn_finalize(const float* __restrict__ gsum, const float* __restrict__ gsumsq,
                            const float* __restrict__ g, const float* __restrict__ be,
                            float* __restrict__ scale, float* __restrict__ shift, int D_)
{
  int c = threadIdx.x;
  if (c >= D_) return;
  float inv = 1.0f / (float)N_NODES;
  float mu = gsum[c] * inv;
  float var = gsumsq[c] * inv - mu * mu;
  float sc = g[c] * rsqrtf(var + 1e-5f);
  scale[c] = sc;
  shift[c] = be[c] - mu * sc;
}

template<int D_, bool ELU>
__global__ void bn_apply(float* __restrict__ h, const float* __restrict__ scale,
                         const float* __restrict__ shift, int total4)
{
  int idx = blockIdx.x * blockDim.x + threadIdx.x;
  if (idx >= total4) return;
  int c0 = (idx * 4) % D_;
  float4 v = *(float4*)&h[(size_t)idx * 4];
  float4 sc = *(const float4*)&scale[c0];
  float4 sh = *(const float4*)&shift[c0];
  float o[4] = {fmaf(v.x, sc.x, sh.x), fmaf(v.y, sc.y, sh.y),
                fmaf(v.z, sc.z, sh.z), fmaf(v.w, sc.w, sh.w)};
  if (ELU) {
    #pragma unroll
    for (int j = 0; j < 4; ++j) o[j] = o[j] > 0.f ? o[j] : __expf(o[j]) - 1.f;
  }
  *(float4*)&h[(size_t)idx * 4] = make_float4(o[0], o[1], o[2], o[3]);
}

// ---------------- graph pooling (mean + max per graph)
__global__ void pool_kernel(const float* __restrict__ h3, const int* __restrict__ batch,
                            float* __restrict__ psum, unsigned* __restrict__ pmax,
                            int* __restrict__ pcnt)
{
  int idx = blockIdx.x * blockDim.x + threadIdx.x;
  if (idx >= N_NODES * C_DIM) return;
  int r = idx >> 6;
  int c = idx & 63;
  int g = batch[r];
  float v = h3[idx];
  atomicAdd(&psum[g * 64 + c], v);
  atomicMax(&pmax[g * 64 + c], fenc(v));
  if (c == 0) atomicAdd(&pcnt[g], 1);
}

// ---------------- classifier MLP on pooled features
__global__ __launch_bounds__(128) void mlp_kernel(
    const float* __restrict__ psum, const unsigned* __restrict__ pmax,
    const int* __restrict__ pcnt, const float* __restrict__ Wc1,
    const float* __restrict__ bc1, const float* __restrict__ Wc2,
    const float* __restrict__ bc2, float* __restrict__ outp)
{
  __shared__ float pooled[128];
  __shared__ float hid[64];
  int gI = blockIdx.x;
  int t = threadIdx.x;
  if (t < 64) {
    float cnt = fmaxf((float)pcnt[gI], 1.0f);
    pooled[t] = psum[gI * 64 + t] / cnt;
  } else {
    pooled[t] = fdec(pmax[gI * 64 + (t - 64)]);
  }
  __syncthreads();
  if (t < 64) {
    float a = 0.f;
    #pragma unroll 8
    for (int k = 0; k < 128; ++k) a = fmaf(pooled[k], Wc1[k * 64 + t], a);
    a += bc1[t];
    a = fmaxf(a, 0.f);
    hid[t] = a * Wc2[t];
  }
  __syncthreads();
  if (t == 0) {
    float s = 0.f;
    for (int k = 0; k < 64; ++k) s += hid[k];
    outp[gI] = s + bc2[0];
  }
}

extern "C" void kernel_launch(void* const* d_in, const int* in_sizes, int n_in,
                              void* d_out, int out_size, void* d_ws, size_t ws_size,
                              hipStream_t stream)
{
  const float* x    = (const float*)d_in[0];
  const int*   ei   = (const int*)d_in[1];
  const int*   batch= (const int*)d_in[2];
  const float* Wl1  = (const float*)d_in[3];
  const float* Wr1  = (const float*)d_in[4];
  const float* att1 = (const float*)d_in[5];
  // b1 (d_in[6]) cancels in the following BatchNorm -> unused
  const float* g1   = (const float*)d_in[7];
  const float* be1  = (const float*)d_in[8];
  const float* Wl2  = (const float*)d_in[9];
  const float* Wr2  = (const float*)d_in[10];
  const float* att2 = (const float*)d_in[11];
  const float* g2   = (const float*)d_in[13];
  const float* be2  = (const float*)d_in[14];
  const float* Wl3  = (const float*)d_in[15];
  const float* Wr3  = (const float*)d_in[16];
  const float* att3 = (const float*)d_in[17];
  const float* g3   = (const float*)d_in[19];
  const float* be3  = (const float*)d_in[20];
  const float* Wc1  = (const float*)d_in[21];
  const float* bc1  = (const float*)d_in[22];
  const float* Wc2  = (const float*)d_in[23];
  const float* bc2  = (const float*)d_in[24];

  const int* srcs = ei;
  const int* dsts = ei + N_EDGES;

  float* ws = (float*)d_ws;
  size_t o = 0;
  float* XL = ws + o;            o += (size_t)N_NODES * HIDD;
  float* XR = ws + o;            o += (size_t)N_NODES * HIDD;
  float* Hb = ws + o;            o += (size_t)N_NODES * HIDD;  // GAT out / next input; L3 out overlays
  float* EB = ws + o;            o += (size_t)ET * N_HEADS;
  unsigned* MEnc = (unsigned*)(ws + o); o += (size_t)N_NODES * N_HEADS;
  float* DEN = ws + o;           o += (size_t)N_NODES * N_HEADS;
  float* GS  = ws + o;           o += 256;
  float* GSQ = ws + o;           o += 256;
  float* SC  = ws + o;           o += 256;
  float* SH  = ws + o;           o += 256;
  float* PSUM = ws + o;          o += N_GRAPHS * 64;
  unsigned* PMAX = (unsigned*)(ws + o); o += N_GRAPHS * 64;
  int* PCNT = (int*)(ws + o);    o += N_GRAPHS;

  const int EDGE_BLOCKS = (ET + 3) / 4;
  const int ROW_BLOCKS = (N_NODES + 63) / 64;
  // zero span covering MEnc, DEN, GS, GSQ in one memset
  const size_t STAT_ZERO_BYTES = ((size_t)N_NODES * N_HEADS * 2 + 512) * 4;

  // ================= layer 1 (16 -> 4x64, concat) =================
  gemm_dual<16, 256><<<dim3(ROW_BLOCKS, 4), 256, 0, stream>>>(x, Wl1, Wr1, XL, XR, N_NODES);
  hipMemsetAsync(Hb, 0, (size_t)N_NODES * HIDD * 4, stream);
  hipMemsetAsync(MEnc, 0, STAT_ZERO_BYTES, stream);
  edge_score<4, 256><<<EDGE_BLOCKS, 256, 0, stream>>>(XL, XR, att1, srcs, dsts, EB, MEnc);
  edge_p<4><<<(ET * 4 + 255) / 256, 256, 0, stream>>>(dsts, EB, MEnc, DEN);
  edge_accum<4, 256><<<EDGE_BLOCKS, 256, 0, stream>>>(XL, EB, DEN, srcs, dsts, Hb);
  bn_stats<256, 64><<<ROW_BLOCKS, 256, 0, stream>>>(Hb, GS, GSQ, N_NODES);
  bn_finalize<<<1, 256, 0, stream>>>(GS, GSQ, g1, be1, SC, SH, 256);
  bn_apply<256, true><<<(N_NODES * HIDD / 4 + 255) / 256, 256, 0, stream>>>(Hb, SC, SH, N_NODES * HIDD / 4);

  // ================= layer 2 (256 -> 4x64, concat) =================
  gemm_dual<256, 256><<<dim3(ROW_BLOCKS, 4), 256, 0, stream>>>(Hb, Wl2, Wr2, XL, XR, N_NODES);
  hipMemsetAsync(Hb, 0, (size_t)N_NODES * HIDD * 4, stream);
  hipMemsetAsync(MEnc, 0, STAT_ZERO_BYTES, stream);
  edge_score<4, 256><<<EDGE_BLOCKS, 256, 0, stream>>>(XL, XR, att2, srcs, dsts, EB, MEnc);
  edge_p<4><<<(ET * 4 + 255) / 256, 256, 0, stream>>>(dsts, EB, MEnc, DEN);
  edge_accum<4, 256><<<EDGE_BLOCKS, 256, 0, stream>>>(XL, EB, DEN, srcs, dsts, Hb);
  bn_stats<256, 64><<<ROW_BLOCKS, 256, 0, stream>>>(Hb, GS, GSQ, N_NODES);
  bn_finalize<<<1, 256, 0, stream>>>(GS, GSQ, g2, be2, SC, SH, 256);
  bn_apply<256, true><<<(N_NODES * HIDD / 4 + 255) / 256, 256, 0, stream>>>(Hb, SC, SH, N_NODES * HIDD / 4);

  // ================= layer 3 (256 -> 64, 1 head) =================
  gemm_dual<256, 64><<<dim3(ROW_BLOCKS, 1), 256, 0, stream>>>(Hb, Wl3, Wr3, XL, XR, N_NODES);
  hipMemsetAsync(Hb, 0, (size_t)N_NODES * 64 * 4, stream);  // L3 output overlays Hb
  hipMemsetAsync(MEnc, 0, STAT_ZERO_BYTES, stream);
  edge_score<1, 64><<<EDGE_BLOCKS, 256, 0, stream>>>(XL, XR, att3, srcs, dsts, EB, MEnc);
  edge_p<1><<<(ET + 255) / 256, 256, 0, stream>>>(dsts, EB, MEnc, DEN);
  edge_accum<1, 64><<<EDGE_BLOCKS, 256, 0, stream>>>(XL, EB, DEN, srcs, dsts, Hb);
  bn_stats<64, 256><<<(N_NODES + 255) / 256, 256, 0, stream>>>(Hb, GS, GSQ, N_NODES);
  bn_finalize<<<1, 64, 0, stream>>>(GS, GSQ, g3, be3, SC, SH, 64);
  bn_apply<64, false><<<(N_NODES * 64 / 4 + 255) / 256, 256, 0, stream>>>(Hb, SC, SH, N_NODES * 64 / 4);

  // ================= pooling + classifier =================
  hipMemsetAsync(PSUM, 0, (size_t)(N_GRAPHS * 64 * 2 + N_GRAPHS) * 4, stream);
  pool_kernel<<<(N_NODES * 64 + 255) / 256, 256, 0, stream>>>(Hb, batch, PSUM, PMAX, PCNT);
  mlp_kernel<<<N_GRAPHS, 128, 0, stream>>>(PSUM, PMAX, PCNT, Wc1, bc1, Wc2, bc2, (float*)d_out);
}

// Round 2
// 1499.505 us; speedup vs baseline: 4.7875x; 4.7875x over previous
//
#include <hip/hip_runtime.h>
#include <math.h>

#define N_NODES 50000
#define N_EDGES 800000
#define ET (N_EDGES + N_NODES)
#define N_GRAPHS 200
#define F_INN 16
#define C_DIM 64
#define N_HEADS 4
#define HIDD 256

// ---- order-preserving float<->uint encoding for atomicMax-based segment max.
// memset(0) == smaller than any encoded real float (== -inf init).
__device__ __forceinline__ unsigned fenc(float f) {
  unsigned u = __float_as_uint(f);
  return (u & 0x80000000u) ? ~u : (u | 0x80000000u);
}
__device__ __forceinline__ float fdec(unsigned u) {
  return (u & 0x80000000u) ? __uint_as_float(u & 0x7fffffffu) : __uint_as_float(~u);
}

// ---------------- dual GEMM: Cl = A@Bl, Cr = A@Br  (A: nrows x K, B: K x M)
template<int K, int M>
__global__ __launch_bounds__(256) void gemm_dual(
    const float* __restrict__ A, const float* __restrict__ Bl,
    const float* __restrict__ Br, float* __restrict__ Cl,
    float* __restrict__ Cr, int nrows)
{
  __shared__ __align__(16) float As[16][64];
  __shared__ __align__(16) float Bls[16][64];
  __shared__ __align__(16) float Brs[16][64];
  int tid = threadIdx.x;
  int row0 = blockIdx.x * 64;
  int col0 = blockIdx.y * 64;
  int tr = (tid >> 4) << 2;
  int tc = (tid & 15) << 2;
  float accL[4][4] = {{0.f}}, accR[4][4] = {{0.f}};
  int arow = tid >> 2, ak = (tid & 3) << 2;
  int brow = tid >> 4, bcol = (tid & 15) << 2;
  for (int k0 = 0; k0 < K; k0 += 16) {
    float4 av = make_float4(0.f, 0.f, 0.f, 0.f);
    int gr = row0 + arow;
    if (gr < nrows) av = *(const float4*)&A[(size_t)gr * K + k0 + ak];
    As[ak + 0][arow] = av.x;
    As[ak + 1][arow] = av.y;
    As[ak + 2][arow] = av.z;
    As[ak + 3][arow] = av.w;
    *(float4*)&Bls[brow][bcol] = *(const float4*)&Bl[(size_t)(k0 + brow) * M + col0 + bcol];
    *(float4*)&Brs[brow][bcol] = *(const float4*)&Br[(size_t)(k0 + brow) * M + col0 + bcol];
    __syncthreads();
    #pragma unroll
    for (int k = 0; k < 16; ++k) {
      float4 a = *(const float4*)&As[k][tr];
      float4 bl = *(const float4*)&Bls[k][tc];
      float4 br = *(const float4*)&Brs[k][tc];
      float aa[4] = {a.x, a.y, a.z, a.w};
      float lb[4] = {bl.x, bl.y, bl.z, bl.w};
      float rb[4] = {br.x, br.y, br.z, br.w};
      #pragma unroll
      for (int ii = 0; ii < 4; ++ii)
        #pragma unroll
        for (int jj = 0; jj < 4; ++jj) {
          accL[ii][jj] = fmaf(aa[ii], lb[jj], accL[ii][jj]);
          accR[ii][jj] = fmaf(aa[ii], rb[jj], accR[ii][jj]);
        }
    }
    __syncthreads();
  }
  #pragma unroll
  for (int ii = 0; ii < 4; ++ii) {
    int gr = row0 + tr + ii;
    if (gr < nrows) {
      *(float4*)&Cl[(size_t)gr * M + col0 + tc] =
          make_float4(accL[ii][0], accL[ii][1], accL[ii][2], accL[ii][3]);
      *(float4*)&Cr[(size_t)gr * M + col0 + tc] =
          make_float4(accR[ii][0], accR[ii][1], accR[ii][2], accR[ii][3]);
    }
  }
}

// ---------------- CSR build: histogram of dst -> exclusive scan -> scatter src
__global__ void hist_kernel(const int* __restrict__ dsts, int* __restrict__ curs) {
  int i = blockIdx.x * blockDim.x + threadIdx.x;
  if (i >= ET) return;
  int d = (i < N_EDGES) ? dsts[i] : i - N_EDGES;
  atomicAdd(&curs[d], 1);
}

// single-block scan: converts curs (=deg) into row starts in-place; fills rows[0..N]
__global__ __launch_bounds__(1024) void scan_kernel(int* __restrict__ curs,
                                                    int* __restrict__ rows) {
  __shared__ int part[1024];
  constexpr int CHUNK = (N_NODES + 1023) / 1024;  // 49
  int t = threadIdx.x;
  int lo = t * CHUNK, hi = min(lo + CHUNK, N_NODES);
  int s = 0;
  for (int i = lo; i < hi; ++i) s += curs[i];
  part[t] = s;
  __syncthreads();
  for (int off = 1; off < 1024; off <<= 1) {
    int v = (t >= off) ? part[t - off] : 0;
    __syncthreads();
    part[t] += v;
    __syncthreads();
  }
  int base = (t > 0) ? part[t - 1] : 0;
  for (int i = lo; i < hi; ++i) {
    int dg = curs[i];
    rows[i] = base;
    curs[i] = base;
    base += dg;
  }
  if (t == 1023) rows[N_NODES] = base;
}

__global__ void scatter_kernel(const int* __restrict__ srcs, const int* __restrict__ dsts,
                               int* __restrict__ curs, int* __restrict__ esrc) {
  int i = blockIdx.x * blockDim.x + threadIdx.x;
  if (i >= ET) return;
  int s, d;
  if (i < N_EDGES) { s = srcs[i]; d = dsts[i]; } else { s = d = i - N_EDGES; }
  int pos = atomicAdd(&curs[d], 1);
  esrc[pos] = s;
}

// ---------------- pass A: per-dst scores + online softmax (m, denom); no atomics
template<int HEADS_, int D_>
__global__ __launch_bounds__(256) void score_csr(
    const float* __restrict__ xl, const float* __restrict__ xr,
    const float* __restrict__ att, const int* __restrict__ rows,
    const int* __restrict__ esrc, float* __restrict__ eb,
    float* __restrict__ mbuf, float* __restrict__ den)
{
  int d = blockIdx.x * 4 + (threadIdx.x >> 6);
  if (d >= N_NODES) return;
  int lane = threadIdx.x & 63;
  int beg = rows[d], end = rows[d + 1];
  if constexpr (D_ == 256) {
    float4 xrv = *(const float4*)&xr[(size_t)d * 256 + lane * 4];
    float4 w = *(const float4*)&att[lane * 4];
    int h = lane >> 4;
    float m = -INFINITY, s = 0.f;
    for (int p = beg; p < end; ++p) {
      int src = esrc[p];
      float4 a = *(const float4*)&xl[(size_t)src * 256 + lane * 4];
      float v0 = a.x + xrv.x, v1 = a.y + xrv.y, v2 = a.z + xrv.z, v3 = a.w + xrv.w;
      v0 = v0 > 0.f ? v0 : 0.2f * v0;
      v1 = v1 > 0.f ? v1 : 0.2f * v1;
      v2 = v2 > 0.f ? v2 : 0.2f * v2;
      v3 = v3 > 0.f ? v3 : 0.2f * v3;
      float acc = fmaf(v0, w.x, fmaf(v1, w.y, fmaf(v2, w.z, v3 * w.w)));
      acc += __shfl_xor(acc, 1);
      acc += __shfl_xor(acc, 2);
      acc += __shfl_xor(acc, 4);
      acc += __shfl_xor(acc, 8);
      if (acc > m) { s *= __expf(m - acc); m = acc; }
      s += __expf(acc - m);
      if ((lane & 15) == 0) eb[(size_t)p * 4 + h] = acc;
    }
    if ((lane & 15) == 0) { mbuf[d * 4 + h] = m; den[d * 4 + h] = s; }
  } else {  // 1 head, D=64
    float xrv = xr[(size_t)d * 64 + lane];
    float w = att[lane];
    float m = -INFINITY, s = 0.f;
    for (int p = beg; p < end; ++p) {
      int src = esrc[p];
      float v = xl[(size_t)src * 64 + lane] + xrv;
      v = v > 0.f ? v : 0.2f * v;
      float acc = v * w;
      acc += __shfl_xor(acc, 1);
      acc += __shfl_xor(acc, 2);
      acc += __shfl_xor(acc, 4);
      acc += __shfl_xor(acc, 8);
      acc += __shfl_xor(acc, 16);
      acc += __shfl_xor(acc, 32);
      if (acc > m) { s *= __expf(m - acc); m = acc; }
      s += __expf(acc - m);
      if (lane == 0) eb[p] = acc;
    }
    if (lane == 0) { mbuf[d] = m; den[d] = s; }
  }
}

// ---------------- pass C: per-dst aggregate alpha*xl[src]; register acc, one store
template<int HEADS_, int D_>
__global__ __launch_bounds__(256) void aggregate_csr(
    const float* __restrict__ xl, const float* __restrict__ eb,
    const float* __restrict__ mbuf, const float* __restrict__ den,
    const int* __restrict__ rows, const int* __restrict__ esrc,
    float* __restrict__ out)
{
  int d = blockIdx.x * 4 + (threadIdx.x >> 6);
  if (d >= N_NODES) return;
  int lane = threadIdx.x & 63;
  int beg = rows[d], end = rows[d + 1];
  if constexpr (D_ == 256) {
    int h = lane >> 4;
    float m = mbuf[d * 4 + h];
    float inv = 1.f / (den[d * 4 + h] + 1e-16f);
    float a0 = 0.f, a1 = 0.f, a2 = 0.f, a3 = 0.f;
    for (int p = beg; p < end; ++p) {
      int src = esrc[p];
      float alpha = __expf(eb[(size_t)p * 4 + h] - m) * inv;
      float4 a = *(const float4*)&xl[(size_t)src * 256 + lane * 4];
      a0 = fmaf(alpha, a.x, a0);
      a1 = fmaf(alpha, a.y, a1);
      a2 = fmaf(alpha, a.z, a2);
      a3 = fmaf(alpha, a.w, a3);
    }
    *(float4*)&out[(size_t)d * 256 + lane * 4] = make_float4(a0, a1, a2, a3);
  } else {
    float m = mbuf[d];
    float inv = 1.f / (den[d] + 1e-16f);
    float acc = 0.f;
    for (int p = beg; p < end; ++p) {
      int src = esrc[p];
      float alpha = __expf(eb[p] - m) * inv;
      acc = fmaf(alpha, xl[(size_t)src * 64 + lane], acc);
    }
    out[(size_t)d * 64 + lane] = acc;
  }
}

// ---------------- BN statistics (per-channel sum / sumsq)
template<int D_, int RPB>
__global__ __launch_bounds__(256) void bn_stats(const float* __restrict__ h,
    float* __restrict__ gsum, float* __restrict__ gsumsq, int nrows)
{
  constexpr int RG = 256 / D_;
  int c = threadIdx.x % D_;
  int rg = threadIdx.x / D_;
  int r0 = blockIdx.x * RPB;
  float s = 0.f, sq = 0.f;
  int rend = min(r0 + RPB, nrows);
  for (int r = r0 + rg; r < rend; r += RG) {
    float v = h[(size_t)r * D_ + c];
    s += v;
    sq = fmaf(v, v, sq);
  }
  atomicAdd(&gsum[c], s);
  atomicAdd(&gsumsq[c], sq);
}

__global__ void bn_finalize(const float* __restrict__ gsum, const float* __restrict__ gsumsq,
                            const float* __restrict__ g, const float* __restrict__ be,
                            float* __restrict__ scale, float* __restrict__ shift, int D_)
{
  int c = threadIdx.x;
  if (c >= D_) return;
  float inv = 1.0f / (float)N_NODES;
  float mu = gsum[c] * inv;
  float var = gsumsq[c] * inv - mu * mu;
  float sc = g[c] * rsqrtf(var + 1e-5f);
  scale[c] = sc;
  shift[c] = be[c] - mu * sc;
}

template<int D_, bool ELU>
__global__ void bn_apply(float* __restrict__ h, const float* __restrict__ scale,
                         const float* __restrict__ shift, int total4)
{
  int idx = blockIdx.x * blockDim.x + threadIdx.x;
  if (idx >= total4) return;
  int c0 = (idx * 4) % D_;
  float4 v = *(float4*)&h[(size_t)idx * 4];
  float4 sc = *(const float4*)&scale[c0];
  float4 sh = *(const float4*)&shift[c0];
  float o[4] = {fmaf(v.x, sc.x, sh.x), fmaf(v.y, sc.y, sh.y),
                fmaf(v.z, sc.z, sh.z), fmaf(v.w, sc.w, sh.w)};
  if (ELU) {
    #pragma unroll
    for (int j = 0; j < 4; ++j) o[j] = o[j] > 0.f ? o[j] : __expf(o[j]) - 1.f;
  }
  *(float4*)&h[(size_t)idx * 4] = make_float4(o[0], o[1], o[2], o[3]);
}

// ---------------- graph pooling (mean + max per graph)
__global__ void pool_kernel(const float* __restrict__ h3, const int* __restrict__ batch,
                            float* __restrict__ psum, unsigned* __restrict__ pmax,
                            int* __restrict__ pcnt)
{
  int idx = blockIdx.x * blockDim.x + threadIdx.x;
  if (idx >= N_NODES * C_DIM) return;
  int r = idx >> 6;
  int c = idx & 63;
  int g = batch[r];
  float v = h3[idx];
  atomicAdd(&psum[g * 64 + c], v);
  atomicMax(&pmax[g * 64 + c], fenc(v));
  if (c == 0) atomicAdd(&pcnt[g], 1);
}

// ---------------- classifier MLP on pooled features
__global__ __launch_bounds__(128) void mlp_kernel(
    const float* __restrict__ psum, const unsigned* __restrict__ pmax,
    const int* __restrict__ pcnt, const float* __restrict__ Wc1,
    const float* __restrict__ bc1, const float* __restrict__ Wc2,
    const float* __restrict__ bc2, float* __restrict__ outp)
{
  __shared__ float pooled[128];
  __shared__ float hid[64];
  int gI = blockIdx.x;
  int t = threadIdx.x;
  if (t < 64) {
    float cnt = fmaxf((float)pcnt[gI], 1.0f);
    pooled[t] = psum[gI * 64 + t] / cnt;
  } else {
    pooled[t] = fdec(pmax[gI * 64 + (t - 64)]);
  }
  __syncthreads();
  if (t < 64) {
    float a = 0.f;
    #pragma unroll 8
    for (int k = 0; k < 128; ++k) a = fmaf(pooled[k], Wc1[k * 64 + t], a);
    a += bc1[t];
    a = fmaxf(a, 0.f);
    hid[t] = a * Wc2[t];
  }
  __syncthreads();
  if (t == 0) {
    float s = 0.f;
    for (int k = 0; k < 64; ++k) s += hid[k];
    outp[gI] = s + bc2[0];
  }
}

extern "C" void kernel_launch(void* const* d_in, const int* in_sizes, int n_in,
                              void* d_out, int out_size, void* d_ws, size_t ws_size,
                              hipStream_t stream)
{
  const float* x    = (const float*)d_in[0];
  const int*   ei   = (const int*)d_in[1];
  const int*   batch= (const int*)d_in[2];
  const float* Wl1  = (const float*)d_in[3];
  const float* Wr1  = (const float*)d_in[4];
  const float* att1 = (const float*)d_in[5];
  // b1/b2/b3 cancel in the following BatchNorm -> unused
  const float* g1   = (const float*)d_in[7];
  const float* be1  = (const float*)d_in[8];
  const float* Wl2  = (const float*)d_in[9];
  const float* Wr2  = (const float*)d_in[10];
  const float* att2 = (const float*)d_in[11];
  const float* g2   = (const float*)d_in[13];
  const float* be2  = (const float*)d_in[14];
  const float* Wl3  = (const float*)d_in[15];
  const float* Wr3  = (const float*)d_in[16];
  const float* att3 = (const float*)d_in[17];
  const float* g3   = (const float*)d_in[19];
  const float* be3  = (const float*)d_in[20];
  const float* Wc1  = (const float*)d_in[21];
  const float* bc1  = (const float*)d_in[22];
  const float* Wc2  = (const float*)d_in[23];
  const float* bc2  = (const float*)d_in[24];

  const int* srcs = ei;
  const int* dsts = ei + N_EDGES;

  float* ws = (float*)d_ws;
  size_t o = 0;
  float* XL = ws + o;            o += (size_t)N_NODES * HIDD;
  float* XR = ws + o;            o += (size_t)N_NODES * HIDD;
  float* Hb = ws + o;            o += (size_t)N_NODES * HIDD;
  float* EB = ws + o;            o += (size_t)ET * N_HEADS;
  int* ESRC = (int*)(ws + o);    o += ET;
  int* ROWS = (int*)(ws + o);    o += N_NODES + 1;
  int* CURS = (int*)(ws + o);    o += N_NODES;
  float* MBUF = ws + o;          o += (size_t)N_NODES * N_HEADS;
  float* DEN = ws + o;           o += (size_t)N_NODES * N_HEADS;
  float* GS  = ws + o;           o += 256;
  float* GSQ = ws + o;           o += 256;
  float* SC  = ws + o;           o += 256;
  float* SH  = ws + o;           o += 256;
  float* PSUM = ws + o;          o += N_GRAPHS * 64;
  unsigned* PMAX = (unsigned*)(ws + o); o += N_GRAPHS * 64;
  int* PCNT = (int*)(ws + o);    o += N_GRAPHS;

  const int ROW_BLOCKS = (N_NODES + 63) / 64;
  const int DST_BLOCKS = (N_NODES + 3) / 4;

  // ================= CSR build (reused by all 3 layers) =================
  hipMemsetAsync(CURS, 0, N_NODES * 4, stream);
  hist_kernel<<<(ET + 255) / 256, 256, 0, stream>>>(dsts, CURS);
  scan_kernel<<<1, 1024, 0, stream>>>(CURS, ROWS);
  scatter_kernel<<<(ET + 255) / 256, 256, 0, stream>>>(srcs, dsts, CURS, ESRC);

  // ================= layer 1 (16 -> 4x64, concat) =================
  gemm_dual<16, 256><<<dim3(ROW_BLOCKS, 4), 256, 0, stream>>>(x, Wl1, Wr1, XL, XR, N_NODES);
  score_csr<4, 256><<<DST_BLOCKS, 256, 0, stream>>>(XL, XR, att1, ROWS, ESRC, EB, MBUF, DEN);
  aggregate_csr<4, 256><<<DST_BLOCKS, 256, 0, stream>>>(XL, EB, MBUF, DEN, ROWS, ESRC, Hb);
  hipMemsetAsync(GS, 0, 512 * 4, stream);
  bn_stats<256, 64><<<ROW_BLOCKS, 256, 0, stream>>>(Hb, GS, GSQ, N_NODES);
  bn_finalize<<<1, 256, 0, stream>>>(GS, GSQ, g1, be1, SC, SH, 256);
  bn_apply<256, true><<<(N_NODES * HIDD / 4 + 255) / 256, 256, 0, stream>>>(Hb, SC, SH, N_NODES * HIDD / 4);

  // ================= layer 2 (256 -> 4x64, concat) =================
  gemm_dual<256, 256><<<dim3(ROW_BLOCKS, 4), 256, 0, stream>>>(Hb, Wl2, Wr2, XL, XR, N_NODES);
  score_csr<4, 256><<<DST_BLOCKS, 256, 0, stream>>>(XL, XR, att2, ROWS, ESRC, EB, MBUF, DEN);
  aggregate_csr<4, 256><<<DST_BLOCKS, 256, 0, stream>>>(XL, EB, MBUF, DEN, ROWS, ESRC, Hb);
  hipMemsetAsync(GS, 0, 512 * 4, stream);
  bn_stats<256, 64><<<ROW_BLOCKS, 256, 0, stream>>>(Hb, GS, GSQ, N_NODES);
  bn_finalize<<<1, 256, 0, stream>>>(GS, GSQ, g2, be2, SC, SH, 256);
  bn_apply<256, true><<<(N_NODES * HIDD / 4 + 255) / 256, 256, 0, stream>>>(Hb, SC, SH, N_NODES * HIDD / 4);

  // ================= layer 3 (256 -> 64, 1 head) =================
  gemm_dual<256, 64><<<dim3(ROW_BLOCKS, 1), 256, 0, stream>>>(Hb, Wl3, Wr3, XL, XR, N_NODES);
  score_csr<1, 64><<<DST_BLOCKS, 256, 0, stream>>>(XL, XR, att3, ROWS, ESRC, EB, MBUF, DEN);
  aggregate_csr<1, 64><<<DST_BLOCKS, 256, 0, stream>>>(XL, EB, MBUF, DEN, ROWS, ESRC, Hb);
  hipMemsetAsync(GS, 0, 512 * 4, stream);
  bn_stats<64, 256><<<(N_NODES + 255) / 256, 256, 0, stream>>>(Hb, GS, GSQ, N_NODES);
  bn_finalize<<<1, 64, 0, stream>>>(GS, GSQ, g3, be3, SC, SH, 64);
  bn_apply<64, false><<<(N_NODES * 64 / 4 + 255) / 256, 256, 0, stream>>>(Hb, SC, SH, N_NODES * 64 / 4);

  // ================= pooling + classifier =================
  hipMemsetAsync(PSUM, 0, (size_t)(N_GRAPHS * 64 * 2 + N_GRAPHS) * 4, stream);
  pool_kernel<<<(N_NODES * 64 + 255) / 256, 256, 0, stream>>>(Hb, batch, PSUM, PMAX, PCNT);
  mlp_kernel<<<N_GRAPHS, 128, 0, stream>>>(PSUM, PMAX, PCNT, Wc1, bc1, Wc2, bc2, (float*)d_out);
}

// Round 3
// 999.309 us; speedup vs baseline: 7.1838x; 1.5005x over previous
//
#include <hip/hip_runtime.h>
#include <math.h>

#define N_NODES 50000
#define N_EDGES 800000
#define ET (N_EDGES + N_NODES)
#define N_GRAPHS 200
#define F_INN 16
#define C_DIM 64
#define N_HEADS 4
#define HIDD 256

// ---------------- dual GEMM: Cl = A'@Bl, Cr = A'@Br  (A: nrows x K, B: K x M)
// TRANS: A' = elu(A*sc + sh) applied on the fly while staging A (BN+ELU fusion).
template<int K, int M, bool TRANS>
__global__ __launch_bounds__(256) void gemm_dual(
    const float* __restrict__ A, const float* __restrict__ Bl,
    const float* __restrict__ Br, float* __restrict__ Cl,
    float* __restrict__ Cr, const float* __restrict__ scp,
    const float* __restrict__ shp, int nrows)
{
  __shared__ __align__(16) float As[16][64];
  __shared__ __align__(16) float Bls[16][64];
  __shared__ __align__(16) float Brs[16][64];
  int tid = threadIdx.x;
  int row0 = blockIdx.x * 64;
  int col0 = blockIdx.y * 64;
  int tr = (tid >> 4) << 2;
  int tc = (tid & 15) << 2;
  float accL[4][4] = {{0.f}}, accR[4][4] = {{0.f}};
  int arow = tid >> 2, ak = (tid & 3) << 2;
  int brow = tid >> 4, bcol = (tid & 15) << 2;
  for (int k0 = 0; k0 < K; k0 += 16) {
    float4 av = make_float4(0.f, 0.f, 0.f, 0.f);
    int gr = row0 + arow;
    if (gr < nrows) {
      av = *(const float4*)&A[(size_t)gr * K + k0 + ak];
      if constexpr (TRANS) {
        float4 sc4 = *(const float4*)&scp[k0 + ak];
        float4 sh4 = *(const float4*)&shp[k0 + ak];
        float t0 = fmaf(av.x, sc4.x, sh4.x);
        float t1 = fmaf(av.y, sc4.y, sh4.y);
        float t2 = fmaf(av.z, sc4.z, sh4.z);
        float t3 = fmaf(av.w, sc4.w, sh4.w);
        av.x = t0 > 0.f ? t0 : __expf(t0) - 1.f;
        av.y = t1 > 0.f ? t1 : __expf(t1) - 1.f;
        av.z = t2 > 0.f ? t2 : __expf(t2) - 1.f;
        av.w = t3 > 0.f ? t3 : __expf(t3) - 1.f;
      }
    }
    As[ak + 0][arow] = av.x;
    As[ak + 1][arow] = av.y;
    As[ak + 2][arow] = av.z;
    As[ak + 3][arow] = av.w;
    *(float4*)&Bls[brow][bcol] = *(const float4*)&Bl[(size_t)(k0 + brow) * M + col0 + bcol];
    *(float4*)&Brs[brow][bcol] = *(const float4*)&Br[(size_t)(k0 + brow) * M + col0 + bcol];
    __syncthreads();
    #pragma unroll
    for (int k = 0; k < 16; ++k) {
      float4 a = *(const float4*)&As[k][tr];
      float4 bl = *(const float4*)&Bls[k][tc];
      float4 br = *(const float4*)&Brs[k][tc];
      float aa[4] = {a.x, a.y, a.z, a.w};
      float lb[4] = {bl.x, bl.y, bl.z, bl.w};
      float rb[4] = {br.x, br.y, br.z, br.w};
      #pragma unroll
      for (int ii = 0; ii < 4; ++ii)
        #pragma unroll
        for (int jj = 0; jj < 4; ++jj) {
          accL[ii][jj] = fmaf(aa[ii], lb[jj], accL[ii][jj]);
          accR[ii][jj] = fmaf(aa[ii], rb[jj], accR[ii][jj]);
        }
    }
    __syncthreads();
  }
  #pragma unroll
  for (int ii = 0; ii < 4; ++ii) {
    int gr = row0 + tr + ii;
    if (gr < nrows) {
      *(float4*)&Cl[(size_t)gr * M + col0 + tc] =
          make_float4(accL[ii][0], accL[ii][1], accL[ii][2], accL[ii][3]);
      *(float4*)&Cr[(size_t)gr * M + col0 + tc] =
          make_float4(accR[ii][0], accR[ii][1], accR[ii][2], accR[ii][3]);
    }
  }
}

// ---------------- CSR build: histogram of dst -> exclusive scan -> scatter src
__global__ void hist_kernel(const int* __restrict__ dsts, int* __restrict__ curs) {
  int i = blockIdx.x * blockDim.x + threadIdx.x;
  if (i >= ET) return;
  int d = (i < N_EDGES) ? dsts[i] : i - N_EDGES;
  atomicAdd(&curs[d], 1);
}

__global__ __launch_bounds__(1024) void scan_kernel(int* __restrict__ curs,
                                                    int* __restrict__ rows) {
  __shared__ int part[1024];
  constexpr int CHUNK = (N_NODES + 1023) / 1024;
  int t = threadIdx.x;
  int lo = t * CHUNK, hi = min(lo + CHUNK, N_NODES);
  int s = 0;
  for (int i = lo; i < hi; ++i) s += curs[i];
  part[t] = s;
  __syncthreads();
  for (int off = 1; off < 1024; off <<= 1) {
    int v = (t >= off) ? part[t - off] : 0;
    __syncthreads();
    part[t] += v;
    __syncthreads();
  }
  int base = (t > 0) ? part[t - 1] : 0;
  for (int i = lo; i < hi; ++i) {
    int dg = curs[i];
    rows[i] = base;
    curs[i] = base;
    base += dg;
  }
  if (t == 1023) rows[N_NODES] = base;
}

__global__ void scatter_kernel(const int* __restrict__ srcs, const int* __restrict__ dsts,
                               int* __restrict__ curs, int* __restrict__ esrc) {
  int i = blockIdx.x * blockDim.x + threadIdx.x;
  if (i >= ET) return;
  int s, d;
  if (i < N_EDGES) { s = srcs[i]; d = dsts[i]; } else { s = d = i - N_EDGES; }
  int pos = atomicAdd(&curs[d], 1);
  esrc[pos] = s;
}

// ---------------- fused flash-attention pass: one wave per dst, online softmax,
// register accumulator, single coalesced store. No score buffer, no atomics.
template<int HEADS_, int D_>
__global__ __launch_bounds__(256) void flash_csr(
    const float* __restrict__ xl, const float* __restrict__ xr,
    const float* __restrict__ att, const int* __restrict__ rows,
    const int* __restrict__ esrc, float* __restrict__ out)
{
  int d = blockIdx.x * 4 + (threadIdx.x >> 6);
  if (d >= N_NODES) return;
  int lane = threadIdx.x & 63;
  int beg = rows[d], end = rows[d + 1];
  if constexpr (D_ == 256) {
    float4 xrv = *(const float4*)&xr[(size_t)d * 256 + lane * 4];
    float4 w = *(const float4*)&att[lane * 4];
    float m = -INFINITY, s = 0.f;
    float a0 = 0.f, a1 = 0.f, a2 = 0.f, a3 = 0.f;
    for (int p = beg; p < end; ++p) {
      int src = esrc[p];
      float4 a = *(const float4*)&xl[(size_t)src * 256 + lane * 4];
      float v0 = a.x + xrv.x, v1 = a.y + xrv.y, v2 = a.z + xrv.z, v3 = a.w + xrv.w;
      v0 = v0 > 0.f ? v0 : 0.2f * v0;
      v1 = v1 > 0.f ? v1 : 0.2f * v1;
      v2 = v2 > 0.f ? v2 : 0.2f * v2;
      v3 = v3 > 0.f ? v3 : 0.2f * v3;
      float e = fmaf(v0, w.x, fmaf(v1, w.y, fmaf(v2, w.z, v3 * w.w)));
      e += __shfl_xor(e, 1);
      e += __shfl_xor(e, 2);
      e += __shfl_xor(e, 4);
      e += __shfl_xor(e, 8);
      float mn = fmaxf(m, e);
      float f = __expf(m - mn);
      float pe = __expf(e - mn);
      s = fmaf(s, f, pe);
      a0 = fmaf(a0, f, pe * a.x);
      a1 = fmaf(a1, f, pe * a.y);
      a2 = fmaf(a2, f, pe * a.z);
      a3 = fmaf(a3, f, pe * a.w);
      m = mn;
    }
    float inv = 1.f / (s + 1e-16f);
    *(float4*)&out[(size_t)d * 256 + lane * 4] =
        make_float4(a0 * inv, a1 * inv, a2 * inv, a3 * inv);
  } else {  // 1 head, D=64
    float xrv = xr[(size_t)d * 64 + lane];
    float w = att[lane];
    float m = -INFINITY, s = 0.f, acc = 0.f;
    for (int p = beg; p < end; ++p) {
      int src = esrc[p];
      float a = xl[(size_t)src * 64 + lane];
      float v = a + xrv;
      v = v > 0.f ? v : 0.2f * v;
      float e = v * w;
      e += __shfl_xor(e, 1);
      e += __shfl_xor(e, 2);
      e += __shfl_xor(e, 4);
      e += __shfl_xor(e, 8);
      e += __shfl_xor(e, 16);
      e += __shfl_xor(e, 32);
      float mn = fmaxf(m, e);
      float f = __expf(m - mn);
      float pe = __expf(e - mn);
      s = fmaf(s, f, pe);
      acc = fmaf(acc, f, pe * a);
      m = mn;
    }
    out[(size_t)d * 64 + lane] = acc / (s + 1e-16f);
  }
}

// ---------------- BN statistics (per-channel sum / sumsq)
template<int D_, int RPB>
__global__ __launch_bounds__(256) void bn_stats(const float* __restrict__ h,
    float* __restrict__ gsum, float* __restrict__ gsumsq, int nrows)
{
  constexpr int RG = 256 / D_;
  int c = threadIdx.x % D_;
  int rg = threadIdx.x / D_;
  int r0 = blockIdx.x * RPB;
  float s = 0.f, sq = 0.f;
  int rend = min(r0 + RPB, nrows);
  for (int r = r0 + rg; r < rend; r += RG) {
    float v = h[(size_t)r * D_ + c];
    s += v;
    sq = fmaf(v, v, sq);
  }
  atomicAdd(&gsum[c], s);
  atomicAdd(&gsumsq[c], sq);
}

__global__ void bn_finalize(const float* __restrict__ gsum, const float* __restrict__ gsumsq,
                            const float* __restrict__ g, const float* __restrict__ be,
                            float* __restrict__ scale, float* __restrict__ shift, int D_)
{
  int c = threadIdx.x;
  if (c >= D_) return;
  float inv = 1.0f / (float)N_NODES;
  float mu = gsum[c] * inv;
  float var = gsumsq[c] * inv - mu * mu;
  float sc = g[c] * rsqrtf(var + 1e-5f);
  scale[c] = sc;
  shift[c] = be[c] - mu * sc;
}

// ---------------- fused pooling (BN applied inline) + classifier MLP.
// batch is sorted: one block per graph, binary-search the node range. No atomics.
__global__ __launch_bounds__(256) void pool_mlp(
    const float* __restrict__ h3, const int* __restrict__ batch,
    const float* __restrict__ sc, const float* __restrict__ sh,
    const float* __restrict__ Wc1, const float* __restrict__ bc1,
    const float* __restrict__ Wc2, const float* __restrict__ bc2,
    float* __restrict__ outp)
{
  int g = blockIdx.x;
  int t = threadIdx.x;
  int lane = t & 63, w = t >> 6;
  int lo, hi;
  {
    int a = 0, b = N_NODES;
    while (a < b) { int mid = (a + b) >> 1; if (batch[mid] < g) a = mid + 1; else b = mid; }
    lo = a;
    b = N_NODES;
    while (a < b) { int mid = (a + b) >> 1; if (batch[mid] < g + 1) a = mid + 1; else b = mid; }
    hi = a;
  }
  float scl = sc[lane], shf = sh[lane];
  float s = 0.f, mx = -INFINITY;
  for (int r = lo + w; r < hi; r += 4) {
    float v = fmaf(h3[(size_t)r * 64 + lane], scl, shf);
    s += v;
    mx = fmaxf(mx, v);
  }
  __shared__ float ssum[4][64];
  __shared__ float smax[4][64];
  __shared__ float pooled[128];
  ssum[w][lane] = s;
  smax[w][lane] = mx;
  __syncthreads();
  if (w == 0) {
    float tot = ssum[0][lane] + ssum[1][lane] + ssum[2][lane] + ssum[3][lane];
    float m4 = fmaxf(fmaxf(smax[0][lane], smax[1][lane]),
                     fmaxf(smax[2][lane], smax[3][lane]));
    float cnt = (float)(hi - lo);
    pooled[lane] = tot / fmaxf(cnt, 1.f);
    pooled[64 + lane] = m4;
  }
  __syncthreads();
  if (w == 0) {
    float a = bc1[lane];
    #pragma unroll 8
    for (int k = 0; k < 128; ++k) a = fmaf(pooled[k], Wc1[k * 64 + lane], a);
    a = fmaxf(a, 0.f);
    float v = a * Wc2[lane];
    v += __shfl_xor(v, 1);
    v += __shfl_xor(v, 2);
    v += __shfl_xor(v, 4);
    v += __shfl_xor(v, 8);
    v += __shfl_xor(v, 16);
    v += __shfl_xor(v, 32);
    if (lane == 0) outp[g] = v + bc2[0];
  }
}

extern "C" void kernel_launch(void* const* d_in, const int* in_sizes, int n_in,
                              void* d_out, int out_size, void* d_ws, size_t ws_size,
                              hipStream_t stream)
{
  const float* x    = (const float*)d_in[0];
  const int*   ei   = (const int*)d_in[1];
  const int*   batch= (const int*)d_in[2];
  const float* Wl1  = (const float*)d_in[3];
  const float* Wr1  = (const float*)d_in[4];
  const float* att1 = (const float*)d_in[5];
  // b1/b2/b3 cancel in the following BatchNorm -> unused
  const float* g1   = (const float*)d_in[7];
  const float* be1  = (const float*)d_in[8];
  const float* Wl2  = (const float*)d_in[9];
  const float* Wr2  = (const float*)d_in[10];
  const float* att2 = (const float*)d_in[11];
  const float* g2   = (const float*)d_in[13];
  const float* be2  = (const float*)d_in[14];
  const float* Wl3  = (const float*)d_in[15];
  const float* Wr3  = (const float*)d_in[16];
  const float* att3 = (const float*)d_in[17];
  const float* g3   = (const float*)d_in[19];
  const float* be3  = (const float*)d_in[20];
  const float* Wc1  = (const float*)d_in[21];
  const float* bc1  = (const float*)d_in[22];
  const float* Wc2  = (const float*)d_in[23];
  const float* bc2  = (const float*)d_in[24];

  const int* srcs = ei;
  const int* dsts = ei + N_EDGES;

  float* ws = (float*)d_ws;
  size_t o = 0;
  float* XL = ws + o;            o += (size_t)N_NODES * HIDD;
  float* XR = ws + o;            o += (size_t)N_NODES * HIDD;
  float* Hb = ws + o;            o += (size_t)N_NODES * HIDD;
  int* ESRC = (int*)(ws + o);    o += ET;
  int* ROWS = (int*)(ws + o);    o += N_NODES + 1;
  int* CURS = (int*)(ws + o);    o += N_NODES;
  float* GS  = ws + o;           o += 256;
  float* GSQ = ws + o;           o += 256;
  float* SC  = ws + o;           o += 256;
  float* SH  = ws + o;           o += 256;

  const int ROW_BLOCKS = (N_NODES + 63) / 64;
  const int DST_BLOCKS = (N_NODES + 3) / 4;

  // ================= CSR build (reused by all 3 layers) =================
  hipMemsetAsync(CURS, 0, N_NODES * 4, stream);
  hist_kernel<<<(ET + 255) / 256, 256, 0, stream>>>(dsts, CURS);
  scan_kernel<<<1, 1024, 0, stream>>>(CURS, ROWS);
  scatter_kernel<<<(ET + 255) / 256, 256, 0, stream>>>(srcs, dsts, CURS, ESRC);

  // ================= layer 1 (16 -> 4x64, concat) =================
  gemm_dual<16, 256, false><<<dim3(ROW_BLOCKS, 4), 256, 0, stream>>>(
      x, Wl1, Wr1, XL, XR, nullptr, nullptr, N_NODES);
  flash_csr<4, 256><<<DST_BLOCKS, 256, 0, stream>>>(XL, XR, att1, ROWS, ESRC, Hb);
  hipMemsetAsync(GS, 0, 512 * 4, stream);
  bn_stats<256, 64><<<ROW_BLOCKS, 256, 0, stream>>>(Hb, GS, GSQ, N_NODES);
  bn_finalize<<<1, 256, 0, stream>>>(GS, GSQ, g1, be1, SC, SH, 256);

  // ================= layer 2 (256 -> 4x64, concat); BN+ELU fused into A load
  gemm_dual<256, 256, true><<<dim3(ROW_BLOCKS, 4), 256, 0, stream>>>(
      Hb, Wl2, Wr2, XL, XR, SC, SH, N_NODES);
  flash_csr<4, 256><<<DST_BLOCKS, 256, 0, stream>>>(XL, XR, att2, ROWS, ESRC, Hb);
  hipMemsetAsync(GS, 0, 512 * 4, stream);
  bn_stats<256, 64><<<ROW_BLOCKS, 256, 0, stream>>>(Hb, GS, GSQ, N_NODES);
  bn_finalize<<<1, 256, 0, stream>>>(GS, GSQ, g2, be2, SC, SH, 256);

  // ================= layer 3 (256 -> 64, 1 head); BN+ELU fused into A load
  gemm_dual<256, 64, true><<<dim3(ROW_BLOCKS, 1), 256, 0, stream>>>(
      Hb, Wl3, Wr3, XL, XR, SC, SH, N_NODES);
  flash_csr<1, 64><<<DST_BLOCKS, 256, 0, stream>>>(XL, XR, att3, ROWS, ESRC, Hb);
  hipMemsetAsync(GS, 0, 512 * 4, stream);
  bn_stats<64, 256><<<(N_NODES + 255) / 256, 256, 0, stream>>>(Hb, GS, GSQ, N_NODES);
  bn_finalize<<<1, 64, 0, stream>>>(GS, GSQ, g3, be3, SC, SH, 64);

  // ================= fused pooling (BN inline) + classifier =================
  pool_mlp<<<N_GRAPHS, 256, 0, stream>>>(Hb, batch, SC, SH, Wc1, bc1, Wc2, bc2,
                                         (float*)d_out);
}

// Round 4
// 922.215 us; speedup vs baseline: 7.7844x; 1.0836x over previous
//
#include <hip/hip_runtime.h>
#include <math.h>

#define N_NODES 50000
#define N_EDGES 800000
#define ET (N_EDGES + N_NODES)
#define N_GRAPHS 200
#define F_INN 16
#define C_DIM 64
#define N_HEADS 4
#define HIDD 256

typedef __attribute__((ext_vector_type(8))) short short8;
typedef __attribute__((ext_vector_type(4))) float f32x4;

// ---------------- dual GEMM (fp32 vector path, layer 1 only: K=16)
template<int K, int M>
__global__ __launch_bounds__(256) void gemm_dual(
    const float* __restrict__ A, const float* __restrict__ Bl,
    const float* __restrict__ Br, float* __restrict__ Cl,
    float* __restrict__ Cr, int nrows)
{
  __shared__ __align__(16) float As[16][64];
  __shared__ __align__(16) float Bls[16][64];
  __shared__ __align__(16) float Brs[16][64];
  int tid = threadIdx.x;
  int row0 = blockIdx.x * 64;
  int col0 = blockIdx.y * 64;
  int tr = (tid >> 4) << 2;
  int tc = (tid & 15) << 2;
  float accL[4][4] = {{0.f}}, accR[4][4] = {{0.f}};
  int arow = tid >> 2, ak = (tid & 3) << 2;
  int brow = tid >> 4, bcol = (tid & 15) << 2;
  for (int k0 = 0; k0 < K; k0 += 16) {
    float4 av = make_float4(0.f, 0.f, 0.f, 0.f);
    int gr = row0 + arow;
    if (gr < nrows) av = *(const float4*)&A[(size_t)gr * K + k0 + ak];
    As[ak + 0][arow] = av.x;
    As[ak + 1][arow] = av.y;
    As[ak + 2][arow] = av.z;
    As[ak + 3][arow] = av.w;
    *(float4*)&Bls[brow][bcol] = *(const float4*)&Bl[(size_t)(k0 + brow) * M + col0 + bcol];
    *(float4*)&Brs[brow][bcol] = *(const float4*)&Br[(size_t)(k0 + brow) * M + col0 + bcol];
    __syncthreads();
    #pragma unroll
    for (int k = 0; k < 16; ++k) {
      float4 a = *(const float4*)&As[k][tr];
      float4 bl = *(const float4*)&Bls[k][tc];
      float4 br = *(const float4*)&Brs[k][tc];
      float aa[4] = {a.x, a.y, a.z, a.w};
      float lb[4] = {bl.x, bl.y, bl.z, bl.w};
      float rb[4] = {br.x, br.y, br.z, br.w};
      #pragma unroll
      for (int ii = 0; ii < 4; ++ii)
        #pragma unroll
        for (int jj = 0; jj < 4; ++jj) {
          accL[ii][jj] = fmaf(aa[ii], lb[jj], accL[ii][jj]);
          accR[ii][jj] = fmaf(aa[ii], rb[jj], accR[ii][jj]);
        }
    }
    __syncthreads();
  }
  #pragma unroll
  for (int ii = 0; ii < 4; ++ii) {
    int gr = row0 + tr + ii;
    if (gr < nrows) {
      *(float4*)&Cl[(size_t)gr * M + col0 + tc] =
          make_float4(accL[ii][0], accL[ii][1], accL[ii][2], accL[ii][3]);
      *(float4*)&Cr[(size_t)gr * M + col0 + tc] =
          make_float4(accR[ii][0], accR[ii][1], accR[ii][2], accR[ii][3]);
    }
  }
}

// ---------------- bf16x2 split helpers
__device__ __forceinline__ void split_bf16(float a, ushort& hi, ushort& lo) {
  unsigned u = __float_as_uint(a);
  hi = (ushort)(u >> 16);
  float ah = __uint_as_float(u & 0xffff0000u);
  float r = a - ah;                      // exact
  lo = (ushort)(__float_as_uint(r) >> 16);
}

// ---------------- convert activations: h' = elu(h*sc+sh) -> bf16 hi/lo planes
__global__ __launch_bounds__(256) void convertA(
    const float* __restrict__ H, const float* __restrict__ sc,
    const float* __restrict__ sh, ushort* __restrict__ Ah,
    ushort* __restrict__ Al, int total4)
{
  int idx = blockIdx.x * blockDim.x + threadIdx.x;
  if (idx >= total4) return;
  int c0 = (idx * 4) & 255;
  float4 v = *(const float4*)&H[(size_t)idx * 4];
  float4 s4 = *(const float4*)&sc[c0];
  float4 h4 = *(const float4*)&sh[c0];
  float t[4] = {fmaf(v.x, s4.x, h4.x), fmaf(v.y, s4.y, h4.y),
                fmaf(v.z, s4.z, h4.z), fmaf(v.w, s4.w, h4.w)};
  ushort hi[4], lo[4];
  #pragma unroll
  for (int j = 0; j < 4; ++j) {
    float e = t[j] > 0.f ? t[j] : __expf(t[j]) - 1.f;
    split_bf16(e, hi[j], lo[j]);
  }
  *(ushort4*)&Ah[(size_t)idx * 4] = make_ushort4(hi[0], hi[1], hi[2], hi[3]);
  *(ushort4*)&Al[(size_t)idx * 4] = make_ushort4(lo[0], lo[1], lo[2], lo[3]);
}

// ---------------- convert a weight matrix [K][N] -> [half][K/8][N][8] bf16
template<int K, int N>
__global__ void convertB(const float* __restrict__ W, ushort* __restrict__ BTmat) {
  int idx = blockIdx.x * blockDim.x + threadIdx.x;
  if (idx >= K * N) return;
  int k = idx / N, n = idx - k * N;
  ushort hi, lo;
  split_bf16(W[idx], hi, lo);
  size_t dst = ((size_t)(k >> 3) * N + n) * 8 + (k & 7);
  BTmat[dst] = hi;
  BTmat[(size_t)(K / 8) * N * 8 + dst] = lo;
}

// ---------------- MFMA dual GEMM: Cl = A@Bl, Cr = A@Br via bf16x2 split.
// A: [M][256] bf16 hi/lo planes. BT: [mat][half][K/8][N][8]. No LDS, no barriers.
template<int N>
__global__ __launch_bounds__(256) void gemm_mfma_dual(
    const ushort* __restrict__ Ah, const ushort* __restrict__ Al,
    const ushort* __restrict__ BT, float* __restrict__ Cl, float* __restrict__ Cr)
{
  constexpr int K = 256;
  constexpr int PLANE = (K / 8) * N * 8;
  const int wave = threadIdx.x >> 6;
  const int lane = threadIdx.x & 63;
  const int r0 = blockIdx.x * 64 + wave * 16;
  const int col0 = blockIdx.y * 64;
  const int kgrp = lane >> 4;      // 0..3
  const int cn = lane & 15;
  const int arow = min(r0 + cn, N_NODES - 1);
  const size_t abase = (size_t)arow * K;
  const ushort* Blh = BT;
  const ushort* Bll = BT + PLANE;
  const ushort* Brh = BT + 2 * PLANE;
  const ushort* Brl = BT + 3 * PLANE;
  f32x4 accL[4], accR[4];
  #pragma unroll
  for (int t = 0; t < 4; ++t) {
    accL[t] = (f32x4)(0.f);
    accR[t] = (f32x4)(0.f);
  }
  #pragma unroll 2
  for (int k0 = 0; k0 < K; k0 += 32) {
    short8 a_h = *(const short8*)&Ah[abase + k0 + kgrp * 8];
    short8 a_l = *(const short8*)&Al[abase + k0 + kgrp * 8];
    const size_t boff = ((size_t)(k0 >> 3) + kgrp) * (N * 8) + (size_t)cn * 8;
    #pragma unroll
    for (int t = 0; t < 4; ++t) {
      const size_t bo = boff + (size_t)(col0 + 16 * t) * 8;
      short8 blh = *(const short8*)&Blh[bo];
      short8 bll = *(const short8*)&Bll[bo];
      short8 brh = *(const short8*)&Brh[bo];
      short8 brl = *(const short8*)&Brl[bo];
      accL[t] = __builtin_amdgcn_mfma_f32_16x16x32_bf16(a_h, blh, accL[t], 0, 0, 0);
      accL[t] = __builtin_amdgcn_mfma_f32_16x16x32_bf16(a_h, bll, accL[t], 0, 0, 0);
      accL[t] = __builtin_amdgcn_mfma_f32_16x16x32_bf16(a_l, blh, accL[t], 0, 0, 0);
      accR[t] = __builtin_amdgcn_mfma_f32_16x16x32_bf16(a_h, brh, accR[t], 0, 0, 0);
      accR[t] = __builtin_amdgcn_mfma_f32_16x16x32_bf16(a_h, brl, accR[t], 0, 0, 0);
      accR[t] = __builtin_amdgcn_mfma_f32_16x16x32_bf16(a_l, brh, accR[t], 0, 0, 0);
    }
  }
  // C/D layout: col = lane&15, row = (lane>>4)*4 + reg   [m89 verified]
  const int crow0 = r0 + kgrp * 4;
  #pragma unroll
  for (int t = 0; t < 4; ++t) {
    int cc = col0 + 16 * t + cn;
    #pragma unroll
    for (int j = 0; j < 4; ++j) {
      int rr = crow0 + j;
      if (rr < N_NODES) {
        Cl[(size_t)rr * N + cc] = accL[t][j];
        Cr[(size_t)rr * N + cc] = accR[t][j];
      }
    }
  }
}

// ---------------- CSR build: histogram of dst -> exclusive scan -> scatter src
__global__ void hist_kernel(const int* __restrict__ dsts, int* __restrict__ curs) {
  int i = blockIdx.x * blockDim.x + threadIdx.x;
  if (i >= ET) return;
  int d = (i < N_EDGES) ? dsts[i] : i - N_EDGES;
  atomicAdd(&curs[d], 1);
}

__global__ __launch_bounds__(1024) void scan_kernel(int* __restrict__ curs,
                                                    int* __restrict__ rows) {
  __shared__ int part[1024];
  constexpr int CHUNK = (N_NODES + 1023) / 1024;
  int t = threadIdx.x;
  int lo = t * CHUNK, hi = min(lo + CHUNK, N_NODES);
  int s = 0;
  for (int i = lo; i < hi; ++i) s += curs[i];
  part[t] = s;
  __syncthreads();
  for (int off = 1; off < 1024; off <<= 1) {
    int v = (t >= off) ? part[t - off] : 0;
    __syncthreads();
    part[t] += v;
    __syncthreads();
  }
  int base = (t > 0) ? part[t - 1] : 0;
  for (int i = lo; i < hi; ++i) {
    int dg = curs[i];
    rows[i] = base;
    curs[i] = base;
    base += dg;
  }
  if (t == 1023) rows[N_NODES] = base;
}

__global__ void scatter_kernel(const int* __restrict__ srcs, const int* __restrict__ dsts,
                               int* __restrict__ curs, int* __restrict__ esrc) {
  int i = blockIdx.x * blockDim.x + threadIdx.x;
  if (i >= ET) return;
  int s, d;
  if (i < N_EDGES) { s = srcs[i]; d = dsts[i]; } else { s = d = i - N_EDGES; }
  int pos = atomicAdd(&curs[d], 1);
  esrc[pos] = s;
}

// ---------------- fused flash-attention pass: one wave per dst, online softmax,
// register accumulator, single coalesced store. No score buffer, no atomics.
template<int HEADS_, int D_>
__global__ __launch_bounds__(256) void flash_csr(
    const float* __restrict__ xl, const float* __restrict__ xr,
    const float* __restrict__ att, const int* __restrict__ rows,
    const int* __restrict__ esrc, float* __restrict__ out)
{
  int d = blockIdx.x * 4 + (threadIdx.x >> 6);
  if (d >= N_NODES) return;
  int lane = threadIdx.x & 63;
  int beg = rows[d], end = rows[d + 1];
  if constexpr (D_ == 256) {
    float4 xrv = *(const float4*)&xr[(size_t)d * 256 + lane * 4];
    float4 w = *(const float4*)&att[lane * 4];
    float m = -INFINITY, s = 0.f;
    float a0 = 0.f, a1 = 0.f, a2 = 0.f, a3 = 0.f;
    for (int p = beg; p < end; ++p) {
      int src = esrc[p];
      float4 a = *(const float4*)&xl[(size_t)src * 256 + lane * 4];
      float v0 = a.x + xrv.x, v1 = a.y + xrv.y, v2 = a.z + xrv.z, v3 = a.w + xrv.w;
      v0 = v0 > 0.f ? v0 : 0.2f * v0;
      v1 = v1 > 0.f ? v1 : 0.2f * v1;
      v2 = v2 > 0.f ? v2 : 0.2f * v2;
      v3 = v3 > 0.f ? v3 : 0.2f * v3;
      float e = fmaf(v0, w.x, fmaf(v1, w.y, fmaf(v2, w.z, v3 * w.w)));
      e += __shfl_xor(e, 1);
      e += __shfl_xor(e, 2);
      e += __shfl_xor(e, 4);
      e += __shfl_xor(e, 8);
      float mn = fmaxf(m, e);
      float f = __expf(m - mn);
      float pe = __expf(e - mn);
      s = fmaf(s, f, pe);
      a0 = fmaf(a0, f, pe * a.x);
      a1 = fmaf(a1, f, pe * a.y);
      a2 = fmaf(a2, f, pe * a.z);
      a3 = fmaf(a3, f, pe * a.w);
      m = mn;
    }
    float inv = 1.f / (s + 1e-16f);
    *(float4*)&out[(size_t)d * 256 + lane * 4] =
        make_float4(a0 * inv, a1 * inv, a2 * inv, a3 * inv);
  } else {  // 1 head, D=64
    float xrv = xr[(size_t)d * 64 + lane];
    float w = att[lane];
    float m = -INFINITY, s = 0.f, acc = 0.f;
    for (int p = beg; p < end; ++p) {
      int src = esrc[p];
      float a = xl[(size_t)src * 64 + lane];
      float v = a + xrv;
      v = v > 0.f ? v : 0.2f * v;
      float e = v * w;
      e += __shfl_xor(e, 1);
      e += __shfl_xor(e, 2);
      e += __shfl_xor(e, 4);
      e += __shfl_xor(e, 8);
      e += __shfl_xor(e, 16);
      e += __shfl_xor(e, 32);
      float mn = fmaxf(m, e);
      float f = __expf(m - mn);
      float pe = __expf(e - mn);
      s = fmaf(s, f, pe);
      acc = fmaf(acc, f, pe * a);
      m = mn;
    }
    out[(size_t)d * 64 + lane] = acc / (s + 1e-16f);
  }
}

// ---------------- BN statistics (per-channel sum / sumsq)
template<int D_, int RPB>
__global__ __launch_bounds__(256) void bn_stats(const float* __restrict__ h,
    float* __restrict__ gsum, float* __restrict__ gsumsq, int nrows)
{
  constexpr int RG = 256 / D_;
  int c = threadIdx.x % D_;
  int rg = threadIdx.x / D_;
  int r0 = blockIdx.x * RPB;
  float s = 0.f, sq = 0.f;
  int rend = min(r0 + RPB, nrows);
  for (int r = r0 + rg; r < rend; r += RG) {
    float v = h[(size_t)r * D_ + c];
    s += v;
    sq = fmaf(v, v, sq);
  }
  atomicAdd(&gsum[c], s);
  atomicAdd(&gsumsq[c], sq);
}

__global__ void bn_finalize(const float* __restrict__ gsum, const float* __restrict__ gsumsq,
                            const float* __restrict__ g, const float* __restrict__ be,
                            float* __restrict__ scale, float* __restrict__ shift, int D_)
{
  int c = threadIdx.x;
  if (c >= D_) return;
  float inv = 1.0f / (float)N_NODES;
  float mu = gsum[c] * inv;
  float var = gsumsq[c] * inv - mu * mu;
  float sc = g[c] * rsqrtf(var + 1e-5f);
  scale[c] = sc;
  shift[c] = be[c] - mu * sc;
}

// ---------------- fused pooling (BN applied inline) + classifier MLP.
__global__ __launch_bounds__(256) void pool_mlp(
    const float* __restrict__ h3, const int* __restrict__ batch,
    const float* __restrict__ sc, const float* __restrict__ sh,
    const float* __restrict__ Wc1, const float* __restrict__ bc1,
    const float* __restrict__ Wc2, const float* __restrict__ bc2,
    float* __restrict__ outp)
{
  int g = blockIdx.x;
  int t = threadIdx.x;
  int lane = t & 63, w = t >> 6;
  int lo, hi;
  {
    int a = 0, b = N_NODES;
    while (a < b) { int mid = (a + b) >> 1; if (batch[mid] < g) a = mid + 1; else b = mid; }
    lo = a;
    b = N_NODES;
    while (a < b) { int mid = (a + b) >> 1; if (batch[mid] < g + 1) a = mid + 1; else b = mid; }
    hi = a;
  }
  float scl = sc[lane], shf = sh[lane];
  float s = 0.f, mx = -INFINITY;
  for (int r = lo + w; r < hi; r += 4) {
    float v = fmaf(h3[(size_t)r * 64 + lane], scl, shf);
    s += v;
    mx = fmaxf(mx, v);
  }
  __shared__ float ssum[4][64];
  __shared__ float smax[4][64];
  __shared__ float pooled[128];
  ssum[w][lane] = s;
  smax[w][lane] = mx;
  __syncthreads();
  if (w == 0) {
    float tot = ssum[0][lane] + ssum[1][lane] + ssum[2][lane] + ssum[3][lane];
    float m4 = fmaxf(fmaxf(smax[0][lane], smax[1][lane]),
                     fmaxf(smax[2][lane], smax[3][lane]));
    float cnt = (float)(hi - lo);
    pooled[lane] = tot / fmaxf(cnt, 1.f);
    pooled[64 + lane] = m4;
  }
  __syncthreads();
  if (w == 0) {
    float a = bc1[lane];
    #pragma unroll 8
    for (int k = 0; k < 128; ++k) a = fmaf(pooled[k], Wc1[k * 64 + lane], a);
    a = fmaxf(a, 0.f);
    float v = a * Wc2[lane];
    v += __shfl_xor(v, 1);
    v += __shfl_xor(v, 2);
    v += __shfl_xor(v, 4);
    v += __shfl_xor(v, 8);
    v += __shfl_xor(v, 16);
    v += __shfl_xor(v, 32);
    if (lane == 0) outp[g] = v + bc2[0];
  }
}

extern "C" void kernel_launch(void* const* d_in, const int* in_sizes, int n_in,
                              void* d_out, int out_size, void* d_ws, size_t ws_size,
                              hipStream_t stream)
{
  const float* x    = (const float*)d_in[0];
  const int*   ei   = (const int*)d_in[1];
  const int*   batch= (const int*)d_in[2];
  const float* Wl1  = (const float*)d_in[3];
  const float* Wr1  = (const float*)d_in[4];
  const float* att1 = (const float*)d_in[5];
  // b1/b2/b3 cancel in the following BatchNorm -> unused
  const float* g1   = (const float*)d_in[7];
  const float* be1  = (const float*)d_in[8];
  const float* Wl2  = (const float*)d_in[9];
  const float* Wr2  = (const float*)d_in[10];
  const float* att2 = (const float*)d_in[11];
  const float* g2   = (const float*)d_in[13];
  const float* be2  = (const float*)d_in[14];
  const float* Wl3  = (const float*)d_in[15];
  const float* Wr3  = (const float*)d_in[16];
  const float* att3 = (const float*)d_in[17];
  const float* g3   = (const float*)d_in[19];
  const float* be3  = (const float*)d_in[20];
  const float* Wc1  = (const float*)d_in[21];
  const float* bc1  = (const float*)d_in[22];
  const float* Wc2  = (const float*)d_in[23];
  const float* bc2  = (const float*)d_in[24];

  const int* srcs = ei;
  const int* dsts = ei + N_EDGES;

  float* ws = (float*)d_ws;
  size_t o = 0;
  float* XL = ws + o;            o += (size_t)N_NODES * HIDD;
  float* XR = ws + o;            o += (size_t)N_NODES * HIDD;
  float* Hb = ws + o;            o += (size_t)N_NODES * HIDD;
  ushort* AH = (ushort*)(ws + o); o += (size_t)N_NODES * HIDD / 2;
  ushort* AL = (ushort*)(ws + o); o += (size_t)N_NODES * HIDD / 2;
  ushort* BT2 = (ushort*)(ws + o); o += (size_t)4 * 32 * 256 * 8 / 2;   // 2 mats x 2 halves
  ushort* BT3 = (ushort*)(ws + o); o += (size_t)4 * 32 * 64 * 8 / 2;
  int* ESRC = (int*)(ws + o);    o += ET;
  int* ROWS = (int*)(ws + o);    o += N_NODES + 1;
  int* CURS = (int*)(ws + o);    o += N_NODES;
  float* GS  = ws + o;           o += 256;
  float* GSQ = ws + o;           o += 256;
  float* SC  = ws + o;           o += 256;
  float* SH  = ws + o;           o += 256;

  const int ROW_BLOCKS = (N_NODES + 63) / 64;
  const int DST_BLOCKS = (N_NODES + 3) / 4;
  const int A4 = N_NODES * HIDD / 4;
  constexpr int PLANE2 = 32 * 256 * 8;
  constexpr int PLANE3 = 32 * 64 * 8;

  // ================= weight transpose/split (independent; run once up front)
  convertB<256, 256><<<(65536 + 255) / 256, 256, 0, stream>>>(Wl2, BT2);
  convertB<256, 256><<<(65536 + 255) / 256, 256, 0, stream>>>(Wr2, BT2 + 2 * PLANE2);
  convertB<256, 64><<<(16384 + 255) / 256, 256, 0, stream>>>(Wl3, BT3);
  convertB<256, 64><<<(16384 + 255) / 256, 256, 0, stream>>>(Wr3, BT3 + 2 * PLANE3);

  // ================= CSR build (reused by all 3 layers) =================
  hipMemsetAsync(CURS, 0, N_NODES * 4, stream);
  hist_kernel<<<(ET + 255) / 256, 256, 0, stream>>>(dsts, CURS);
  scan_kernel<<<1, 1024, 0, stream>>>(CURS, ROWS);
  scatter_kernel<<<(ET + 255) / 256, 256, 0, stream>>>(srcs, dsts, CURS, ESRC);

  // ================= layer 1 (16 -> 4x64, concat): fp32 vector GEMM ======
  gemm_dual<16, 256><<<dim3(ROW_BLOCKS, 4), 256, 0, stream>>>(
      x, Wl1, Wr1, XL, XR, N_NODES);
  flash_csr<4, 256><<<DST_BLOCKS, 256, 0, stream>>>(XL, XR, att1, ROWS, ESRC, Hb);
  hipMemsetAsync(GS, 0, 512 * 4, stream);
  bn_stats<256, 64><<<ROW_BLOCKS, 256, 0, stream>>>(Hb, GS, GSQ, N_NODES);
  bn_finalize<<<1, 256, 0, stream>>>(GS, GSQ, g1, be1, SC, SH, 256);

  // ================= layer 2 (256 -> 4x64): BN+ELU fused convert, MFMA GEMM
  convertA<<<(A4 + 255) / 256, 256, 0, stream>>>(Hb, SC, SH, AH, AL, A4);
  gemm_mfma_dual<256><<<dim3(ROW_BLOCKS, 4), 256, 0, stream>>>(AH, AL, BT2, XL, XR);
  flash_csr<4, 256><<<DST_BLOCKS, 256, 0, stream>>>(XL, XR, att2, ROWS, ESRC, Hb);
  hipMemsetAsync(GS, 0, 512 * 4, stream);
  bn_stats<256, 64><<<ROW_BLOCKS, 256, 0, stream>>>(Hb, GS, GSQ, N_NODES);
  bn_finalize<<<1, 256, 0, stream>>>(GS, GSQ, g2, be2, SC, SH, 256);

  // ================= layer 3 (256 -> 64, 1 head): MFMA GEMM ==============
  convertA<<<(A4 + 255) / 256, 256, 0, stream>>>(Hb, SC, SH, AH, AL, A4);
  gemm_mfma_dual<64><<<dim3(ROW_BLOCKS, 1), 256, 0, stream>>>(AH, AL, BT3, XL, XR);
  flash_csr<1, 64><<<DST_BLOCKS, 256, 0, stream>>>(XL, XR, att3, ROWS, ESRC, Hb);
  hipMemsetAsync(GS, 0, 512 * 4, stream);
  bn_stats<64, 256><<<(N_NODES + 255) / 256, 256, 0, stream>>>(Hb, GS, GSQ, N_NODES);
  bn_finalize<<<1, 64, 0, stream>>>(GS, GSQ, g3, be3, SC, SH, 64);

  // ================= fused pooling (BN inline) + classifier ==============
  pool_mlp<<<N_GRAPHS, 256, 0, stream>>>(Hb, batch, SC, SH, Wc1, bc1, Wc2, bc2,
                                         (float*)d_out);
}

// Round 5
// 775.267 us; speedup vs baseline: 9.2598x; 1.1895x over previous
//
#include <hip/hip_runtime.h>
#include <math.h>

#define N_NODES 50000
#define N_EDGES 800000
#define ET (N_EDGES + N_NODES)
#define N_GRAPHS 200
#define F_INN 16
#define C_DIM 64
#define N_HEADS 4
#define HIDD 256

typedef __attribute__((ext_vector_type(8))) short short8;
typedef __attribute__((ext_vector_type(4))) float f32x4;

__device__ __forceinline__ float bf2f(ushort u) {
  return __uint_as_float(((unsigned)u) << 16);
}
__device__ __forceinline__ ushort f2bf(float f) {  // round-to-nearest-even
  unsigned u = __float_as_uint(f);
  u += 0x7fff + ((u >> 16) & 1);
  return (ushort)(u >> 16);
}

// ---------------- dual GEMM (fp32 vector path, layer 1 only: K=16)
// Cl written as bf16 (feeds edge gathers), Cr as fp32.
template<int K, int M>
__global__ __launch_bounds__(256) void gemm_dual(
    const float* __restrict__ A, const float* __restrict__ Bl,
    const float* __restrict__ Br, ushort* __restrict__ Clb,
    float* __restrict__ Cr, int nrows)
{
  __shared__ __align__(16) float As[16][64];
  __shared__ __align__(16) float Bls[16][64];
  __shared__ __align__(16) float Brs[16][64];
  int tid = threadIdx.x;
  int row0 = blockIdx.x * 64;
  int col0 = blockIdx.y * 64;
  int tr = (tid >> 4) << 2;
  int tc = (tid & 15) << 2;
  float accL[4][4] = {{0.f}}, accR[4][4] = {{0.f}};
  int arow = tid >> 2, ak = (tid & 3) << 2;
  int brow = tid >> 4, bcol = (tid & 15) << 2;
  for (int k0 = 0; k0 < K; k0 += 16) {
    float4 av = make_float4(0.f, 0.f, 0.f, 0.f);
    int gr = row0 + arow;
    if (gr < nrows) av = *(const float4*)&A[(size_t)gr * K + k0 + ak];
    As[ak + 0][arow] = av.x;
    As[ak + 1][arow] = av.y;
    As[ak + 2][arow] = av.z;
    As[ak + 3][arow] = av.w;
    *(float4*)&Bls[brow][bcol] = *(const float4*)&Bl[(size_t)(k0 + brow) * M + col0 + bcol];
    *(float4*)&Brs[brow][bcol] = *(const float4*)&Br[(size_t)(k0 + brow) * M + col0 + bcol];
    __syncthreads();
    #pragma unroll
    for (int k = 0; k < 16; ++k) {
      float4 a = *(const float4*)&As[k][tr];
      float4 bl = *(const float4*)&Bls[k][tc];
      float4 br = *(const float4*)&Brs[k][tc];
      float aa[4] = {a.x, a.y, a.z, a.w};
      float lb[4] = {bl.x, bl.y, bl.z, bl.w};
      float rb[4] = {br.x, br.y, br.z, br.w};
      #pragma unroll
      for (int ii = 0; ii < 4; ++ii)
        #pragma unroll
        for (int jj = 0; jj < 4; ++jj) {
          accL[ii][jj] = fmaf(aa[ii], lb[jj], accL[ii][jj]);
          accR[ii][jj] = fmaf(aa[ii], rb[jj], accR[ii][jj]);
        }
    }
    __syncthreads();
  }
  #pragma unroll
  for (int ii = 0; ii < 4; ++ii) {
    int gr = row0 + tr + ii;
    if (gr < nrows) {
      *(ushort4*)&Clb[(size_t)gr * M + col0 + tc] =
          make_ushort4(f2bf(accL[ii][0]), f2bf(accL[ii][1]),
                       f2bf(accL[ii][2]), f2bf(accL[ii][3]));
      *(float4*)&Cr[(size_t)gr * M + col0 + tc] =
          make_float4(accR[ii][0], accR[ii][1], accR[ii][2], accR[ii][3]);
    }
  }
}

// ---------------- bf16x2 split helpers
__device__ __forceinline__ void split_bf16(float a, ushort& hi, ushort& lo) {
  unsigned u = __float_as_uint(a);
  hi = (ushort)(u >> 16);
  float ah = __uint_as_float(u & 0xffff0000u);
  float r = a - ah;                      // exact
  lo = (ushort)(__float_as_uint(r) >> 16);
}

// ---------------- convert activations: h' = elu(h*sc+sh) -> bf16 hi/lo planes
__global__ __launch_bounds__(256) void convertA(
    const float* __restrict__ H, const float* __restrict__ sc,
    const float* __restrict__ sh, ushort* __restrict__ Ah,
    ushort* __restrict__ Al, int total4)
{
  int idx = blockIdx.x * blockDim.x + threadIdx.x;
  if (idx >= total4) return;
  int c0 = (idx * 4) & 255;
  float4 v = *(const float4*)&H[(size_t)idx * 4];
  float4 s4 = *(const float4*)&sc[c0];
  float4 h4 = *(const float4*)&sh[c0];
  float t[4] = {fmaf(v.x, s4.x, h4.x), fmaf(v.y, s4.y, h4.y),
                fmaf(v.z, s4.z, h4.z), fmaf(v.w, s4.w, h4.w)};
  ushort hi[4], lo[4];
  #pragma unroll
  for (int j = 0; j < 4; ++j) {
    float e = t[j] > 0.f ? t[j] : __expf(t[j]) - 1.f;
    split_bf16(e, hi[j], lo[j]);
  }
  *(ushort4*)&Ah[(size_t)idx * 4] = make_ushort4(hi[0], hi[1], hi[2], hi[3]);
  *(ushort4*)&Al[(size_t)idx * 4] = make_ushort4(lo[0], lo[1], lo[2], lo[3]);
}

// ---------------- convert a weight matrix [K][N] -> [half][K/8][N][8] bf16
template<int K, int N>
__global__ void convertB(const float* __restrict__ W, ushort* __restrict__ BTmat) {
  int idx = blockIdx.x * blockDim.x + threadIdx.x;
  if (idx >= K * N) return;
  int k = idx / N, n = idx - k * N;
  ushort hi, lo;
  split_bf16(W[idx], hi, lo);
  size_t dst = ((size_t)(k >> 3) * N + n) * 8 + (k & 7);
  BTmat[dst] = hi;
  BTmat[(size_t)(K / 8) * N * 8 + dst] = lo;
}

// ---------------- MFMA dual GEMM: Cl = A@Bl (bf16 out), Cr = A@Br (fp32 out)
// A: [M][256] bf16 hi/lo planes. BT: [mat][half][K/8][N][8]. No LDS, no barriers.
template<int N>
__global__ __launch_bounds__(256) void gemm_mfma_dual(
    const ushort* __restrict__ Ah, const ushort* __restrict__ Al,
    const ushort* __restrict__ BT, ushort* __restrict__ Clb,
    float* __restrict__ Cr)
{
  constexpr int K = 256;
  constexpr int PLANE = (K / 8) * N * 8;
  const int wave = threadIdx.x >> 6;
  const int lane = threadIdx.x & 63;
  const int r0 = blockIdx.x * 64 + wave * 16;
  const int col0 = blockIdx.y * 64;
  const int kgrp = lane >> 4;      // 0..3
  const int cn = lane & 15;
  const int arow = min(r0 + cn, N_NODES - 1);
  const size_t abase = (size_t)arow * K;
  const ushort* Blh = BT;
  const ushort* Bll = BT + PLANE;
  const ushort* Brh = BT + 2 * PLANE;
  const ushort* Brl = BT + 3 * PLANE;
  f32x4 accL[4], accR[4];
  #pragma unroll
  for (int t = 0; t < 4; ++t) {
    accL[t] = (f32x4)(0.f);
    accR[t] = (f32x4)(0.f);
  }
  #pragma unroll 2
  for (int k0 = 0; k0 < K; k0 += 32) {
    short8 a_h = *(const short8*)&Ah[abase + k0 + kgrp * 8];
    short8 a_l = *(const short8*)&Al[abase + k0 + kgrp * 8];
    const size_t boff = ((size_t)(k0 >> 3) + kgrp) * (N * 8) + (size_t)cn * 8;
    #pragma unroll
    for (int t = 0; t < 4; ++t) {
      const size_t bo = boff + (size_t)(col0 + 16 * t) * 8;
      short8 blh = *(const short8*)&Blh[bo];
      short8 bll = *(const short8*)&Bll[bo];
      short8 brh = *(const short8*)&Brh[bo];
      short8 brl = *(const short8*)&Brl[bo];
      accL[t] = __builtin_amdgcn_mfma_f32_16x16x32_bf16(a_h, blh, accL[t], 0, 0, 0);
      accL[t] = __builtin_amdgcn_mfma_f32_16x16x32_bf16(a_h, bll, accL[t], 0, 0, 0);
      accL[t] = __builtin_amdgcn_mfma_f32_16x16x32_bf16(a_l, blh, accL[t], 0, 0, 0);
      accR[t] = __builtin_amdgcn_mfma_f32_16x16x32_bf16(a_h, brh, accR[t], 0, 0, 0);
      accR[t] = __builtin_amdgcn_mfma_f32_16x16x32_bf16(a_h, brl, accR[t], 0, 0, 0);
      accR[t] = __builtin_amdgcn_mfma_f32_16x16x32_bf16(a_l, brh, accR[t], 0, 0, 0);
    }
  }
  // C/D layout: col = lane&15, row = (lane>>4)*4 + reg   [m89 verified]
  const int crow0 = r0 + kgrp * 4;
  #pragma unroll
  for (int t = 0; t < 4; ++t) {
    int cc = col0 + 16 * t + cn;
    #pragma unroll
    for (int j = 0; j < 4; ++j) {
      int rr = crow0 + j;
      if (rr < N_NODES) {
        Clb[(size_t)rr * N + cc] = f2bf(accL[t][j]);
        Cr[(size_t)rr * N + cc] = accR[t][j];
      }
    }
  }
}

// ---------------- CSR build: histogram of dst -> exclusive scan -> scatter src
__global__ void hist_kernel(const int* __restrict__ dsts, int* __restrict__ curs) {
  int i = blockIdx.x * blockDim.x + threadIdx.x;
  if (i >= ET) return;
  int d = (i < N_EDGES) ? dsts[i] : i - N_EDGES;
  atomicAdd(&curs[d], 1);
}

__global__ __launch_bounds__(1024) void scan_kernel(int* __restrict__ curs,
                                                    int* __restrict__ rows) {
  __shared__ int part[1024];
  constexpr int CHUNK = (N_NODES + 1023) / 1024;
  int t = threadIdx.x;
  int lo = t * CHUNK, hi = min(lo + CHUNK, N_NODES);
  int s = 0;
  for (int i = lo; i < hi; ++i) s += curs[i];
  part[t] = s;
  __syncthreads();
  for (int off = 1; off < 1024; off <<= 1) {
    int v = (t >= off) ? part[t - off] : 0;
    __syncthreads();
    part[t] += v;
    __syncthreads();
  }
  int base = (t > 0) ? part[t - 1] : 0;
  for (int i = lo; i < hi; ++i) {
    int dg = curs[i];
    rows[i] = base;
    curs[i] = base;
    base += dg;
  }
  if (t == 1023) rows[N_NODES] = base;
}

__global__ void scatter_kernel(const int* __restrict__ srcs, const int* __restrict__ dsts,
                               int* __restrict__ curs, int* __restrict__ esrc) {
  int i = blockIdx.x * blockDim.x + threadIdx.x;
  if (i >= ET) return;
  int s, d;
  if (i < N_EDGES) { s = srcs[i]; d = dsts[i]; } else { s = d = i - N_EDGES; }
  int pos = atomicAdd(&curs[d], 1);
  esrc[pos] = s;
}

// ---------------- fused flash-attention pass: one wave per dst, online softmax,
// bf16 xl gathers (half traffic), fp32 xr, 2 edges/iter, register accumulator.
template<int HEADS_, int D_>
__global__ __launch_bounds__(256) void flash_csr(
    const ushort* __restrict__ xl, const float* __restrict__ xr,
    const float* __restrict__ att, const int* __restrict__ rows,
    const int* __restrict__ esrc, float* __restrict__ out)
{
  int d = blockIdx.x * 4 + (threadIdx.x >> 6);
  if (d >= N_NODES) return;
  int lane = threadIdx.x & 63;
  int beg = rows[d], end = rows[d + 1];
  if constexpr (D_ == 256) {
    float4 xrv = *(const float4*)&xr[(size_t)d * 256 + lane * 4];
    float4 w = *(const float4*)&att[lane * 4];
    float m = -INFINITY, s = 0.f;
    float a0 = 0.f, a1 = 0.f, a2 = 0.f, a3 = 0.f;
    int p = beg;
    for (; p + 2 <= end; p += 2) {
      int s1 = esrc[p], s2 = esrc[p + 1];
      ushort4 u1 = *(const ushort4*)&xl[(size_t)s1 * 256 + lane * 4];
      ushort4 u2 = *(const ushort4*)&xl[(size_t)s2 * 256 + lane * 4];
      float b10 = bf2f(u1.x), b11 = bf2f(u1.y), b12 = bf2f(u1.z), b13 = bf2f(u1.w);
      float b20 = bf2f(u2.x), b21 = bf2f(u2.y), b22 = bf2f(u2.z), b23 = bf2f(u2.w);
      float v0 = b10 + xrv.x, v1 = b11 + xrv.y, v2 = b12 + xrv.z, v3 = b13 + xrv.w;
      v0 = v0 > 0.f ? v0 : 0.2f * v0;
      v1 = v1 > 0.f ? v1 : 0.2f * v1;
      v2 = v2 > 0.f ? v2 : 0.2f * v2;
      v3 = v3 > 0.f ? v3 : 0.2f * v3;
      float e1 = fmaf(v0, w.x, fmaf(v1, w.y, fmaf(v2, w.z, v3 * w.w)));
      v0 = b20 + xrv.x; v1 = b21 + xrv.y; v2 = b22 + xrv.z; v3 = b23 + xrv.w;
      v0 = v0 > 0.f ? v0 : 0.2f * v0;
      v1 = v1 > 0.f ? v1 : 0.2f * v1;
      v2 = v2 > 0.f ? v2 : 0.2f * v2;
      v3 = v3 > 0.f ? v3 : 0.2f * v3;
      float e2 = fmaf(v0, w.x, fmaf(v1, w.y, fmaf(v2, w.z, v3 * w.w)));
      e1 += __shfl_xor(e1, 1); e2 += __shfl_xor(e2, 1);
      e1 += __shfl_xor(e1, 2); e2 += __shfl_xor(e2, 2);
      e1 += __shfl_xor(e1, 4); e2 += __shfl_xor(e2, 4);
      e1 += __shfl_xor(e1, 8); e2 += __shfl_xor(e2, 8);
      float mn = fmaxf(m, fmaxf(e1, e2));
      float f = __expf(m - mn);
      float p1 = __expf(e1 - mn);
      float p2 = __expf(e2 - mn);
      s = fmaf(s, f, p1 + p2);
      a0 = fmaf(a0, f, fmaf(p1, b10, p2 * b20));
      a1 = fmaf(a1, f, fmaf(p1, b11, p2 * b21));
      a2 = fmaf(a2, f, fmaf(p1, b12, p2 * b22));
      a3 = fmaf(a3, f, fmaf(p1, b13, p2 * b23));
      m = mn;
    }
    if (p < end) {
      int s1 = esrc[p];
      ushort4 u1 = *(const ushort4*)&xl[(size_t)s1 * 256 + lane * 4];
      float b10 = bf2f(u1.x), b11 = bf2f(u1.y), b12 = bf2f(u1.z), b13 = bf2f(u1.w);
      float v0 = b10 + xrv.x, v1 = b11 + xrv.y, v2 = b12 + xrv.z, v3 = b13 + xrv.w;
      v0 = v0 > 0.f ? v0 : 0.2f * v0;
      v1 = v1 > 0.f ? v1 : 0.2f * v1;
      v2 = v2 > 0.f ? v2 : 0.2f * v2;
      v3 = v3 > 0.f ? v3 : 0.2f * v3;
      float e1 = fmaf(v0, w.x, fmaf(v1, w.y, fmaf(v2, w.z, v3 * w.w)));
      e1 += __shfl_xor(e1, 1);
      e1 += __shfl_xor(e1, 2);
      e1 += __shfl_xor(e1, 4);
      e1 += __shfl_xor(e1, 8);
      float mn = fmaxf(m, e1);
      float f = __expf(m - mn);
      float p1 = __expf(e1 - mn);
      s = fmaf(s, f, p1);
      a0 = fmaf(a0, f, p1 * b10);
      a1 = fmaf(a1, f, p1 * b11);
      a2 = fmaf(a2, f, p1 * b12);
      a3 = fmaf(a3, f, p1 * b13);
    }
    float inv = 1.f / (s + 1e-16f);
    *(float4*)&out[(size_t)d * 256 + lane * 4] =
        make_float4(a0 * inv, a1 * inv, a2 * inv, a3 * inv);
  } else {  // 1 head, D=64
    float xrv = xr[(size_t)d * 64 + lane];
    float w = att[lane];
    float m = -INFINITY, s = 0.f, acc = 0.f;
    int p = beg;
    for (; p + 2 <= end; p += 2) {
      int s1 = esrc[p], s2 = esrc[p + 1];
      float b1 = bf2f(xl[(size_t)s1 * 64 + lane]);
      float b2 = bf2f(xl[(size_t)s2 * 64 + lane]);
      float v1 = b1 + xrv, v2 = b2 + xrv;
      v1 = v1 > 0.f ? v1 : 0.2f * v1;
      v2 = v2 > 0.f ? v2 : 0.2f * v2;
      float e1 = v1 * w, e2 = v2 * w;
      e1 += __shfl_xor(e1, 1);  e2 += __shfl_xor(e2, 1);
      e1 += __shfl_xor(e1, 2);  e2 += __shfl_xor(e2, 2);
      e1 += __shfl_xor(e1, 4);  e2 += __shfl_xor(e2, 4);
      e1 += __shfl_xor(e1, 8);  e2 += __shfl_xor(e2, 8);
      e1 += __shfl_xor(e1, 16); e2 += __shfl_xor(e2, 16);
      e1 += __shfl_xor(e1, 32); e2 += __shfl_xor(e2, 32);
      float mn = fmaxf(m, fmaxf(e1, e2));
      float f = __expf(m - mn);
      float p1 = __expf(e1 - mn);
      float p2 = __expf(e2 - mn);
      s = fmaf(s, f, p1 + p2);
      acc = fmaf(acc, f, fmaf(p1, b1, p2 * b2));
      m = mn;
    }
    if (p < end) {
      int s1 = esrc[p];
      float b1 = bf2f(xl[(size_t)s1 * 64 + lane]);
      float v1 = b1 + xrv;
      v1 = v1 > 0.f ? v1 : 0.2f * v1;
      float e1 = v1 * w;
      e1 += __shfl_xor(e1, 1);
      e1 += __shfl_xor(e1, 2);
      e1 += __shfl_xor(e1, 4);
      e1 += __shfl_xor(e1, 8);
      e1 += __shfl_xor(e1, 16);
      e1 += __shfl_xor(e1, 32);
      float mn = fmaxf(m, e1);
      float f = __expf(m - mn);
      float p1 = __expf(e1 - mn);
      s = fmaf(s, f, p1);
      acc = fmaf(acc, f, p1 * b1);
    }
    out[(size_t)d * 64 + lane] = acc / (s + 1e-16f);
  }
}

// ---------------- BN statistics (per-channel sum / sumsq)
template<int D_, int RPB>
__global__ __launch_bounds__(256) void bn_stats(const float* __restrict__ h,
    float* __restrict__ gsum, float* __restrict__ gsumsq, int nrows)
{
  constexpr int RG = 256 / D_;
  int c = threadIdx.x % D_;
  int rg = threadIdx.x / D_;
  int r0 = blockIdx.x * RPB;
  float s = 0.f, sq = 0.f;
  int rend = min(r0 + RPB, nrows);
  for (int r = r0 + rg; r < rend; r += RG) {
    float v = h[(size_t)r * D_ + c];
    s += v;
    sq = fmaf(v, v, sq);
  }
  atomicAdd(&gsum[c], s);
  atomicAdd(&gsumsq[c], sq);
}

__global__ void bn_finalize(const float* __restrict__ gsum, const float* __restrict__ gsumsq,
                            const float* __restrict__ g, const float* __restrict__ be,
                            float* __restrict__ scale, float* __restrict__ shift, int D_)
{
  int c = threadIdx.x;
  if (c >= D_) return;
  float inv = 1.0f / (float)N_NODES;
  float mu = gsum[c] * inv;
  float var = gsumsq[c] * inv - mu * mu;
  float sc = g[c] * rsqrtf(var + 1e-5f);
  scale[c] = sc;
  shift[c] = be[c] - mu * sc;
}

// ---------------- fused pooling (BN applied inline) + classifier MLP.
__global__ __launch_bounds__(256) void pool_mlp(
    const float* __restrict__ h3, const int* __restrict__ batch,
    const float* __restrict__ sc, const float* __restrict__ sh,
    const float* __restrict__ Wc1, const float* __restrict__ bc1,
    const float* __restrict__ Wc2, const float* __restrict__ bc2,
    float* __restrict__ outp)
{
  int g = blockIdx.x;
  int t = threadIdx.x;
  int lane = t & 63, w = t >> 6;
  int lo, hi;
  {
    int a = 0, b = N_NODES;
    while (a < b) { int mid = (a + b) >> 1; if (batch[mid] < g) a = mid + 1; else b = mid; }
    lo = a;
    b = N_NODES;
    while (a < b) { int mid = (a + b) >> 1; if (batch[mid] < g + 1) a = mid + 1; else b = mid; }
    hi = a;
  }
  float scl = sc[lane], shf = sh[lane];
  float s = 0.f, mx = -INFINITY;
  for (int r = lo + w; r < hi; r += 4) {
    float v = fmaf(h3[(size_t)r * 64 + lane], scl, shf);
    s += v;
    mx = fmaxf(mx, v);
  }
  __shared__ float ssum[4][64];
  __shared__ float smax[4][64];
  __shared__ float pooled[128];
  ssum[w][lane] = s;
  smax[w][lane] = mx;
  __syncthreads();
  if (w == 0) {
    float tot = ssum[0][lane] + ssum[1][lane] + ssum[2][lane] + ssum[3][lane];
    float m4 = fmaxf(fmaxf(smax[0][lane], smax[1][lane]),
                     fmaxf(smax[2][lane], smax[3][lane]));
    float cnt = (float)(hi - lo);
    pooled[lane] = tot / fmaxf(cnt, 1.f);
    pooled[64 + lane] = m4;
  }
  __syncthreads();
  if (w == 0) {
    float a = bc1[lane];
    #pragma unroll 8
    for (int k = 0; k < 128; ++k) a = fmaf(pooled[k], Wc1[k * 64 + lane], a);
    a = fmaxf(a, 0.f);
    float v = a * Wc2[lane];
    v += __shfl_xor(v, 1);
    v += __shfl_xor(v, 2);
    v += __shfl_xor(v, 4);
    v += __shfl_xor(v, 8);
    v += __shfl_xor(v, 16);
    v += __shfl_xor(v, 32);
    if (lane == 0) outp[g] = v + bc2[0];
  }
}

extern "C" void kernel_launch(void* const* d_in, const int* in_sizes, int n_in,
                              void* d_out, int out_size, void* d_ws, size_t ws_size,
                              hipStream_t stream)
{
  const float* x    = (const float*)d_in[0];
  const int*   ei   = (const int*)d_in[1];
  const int*   batch= (const int*)d_in[2];
  const float* Wl1  = (const float*)d_in[3];
  const float* Wr1  = (const float*)d_in[4];
  const float* att1 = (const float*)d_in[5];
  // b1/b2/b3 cancel in the following BatchNorm -> unused
  const float* g1   = (const float*)d_in[7];
  const float* be1  = (const float*)d_in[8];
  const float* Wl2  = (const float*)d_in[9];
  const float* Wr2  = (const float*)d_in[10];
  const float* att2 = (const float*)d_in[11];
  const float* g2   = (const float*)d_in[13];
  const float* be2  = (const float*)d_in[14];
  const float* Wl3  = (const float*)d_in[15];
  const float* Wr3  = (const float*)d_in[16];
  const float* att3 = (const float*)d_in[17];
  const float* g3   = (const float*)d_in[19];
  const float* be3  = (const float*)d_in[20];
  const float* Wc1  = (const float*)d_in[21];
  const float* bc1  = (const float*)d_in[22];
  const float* Wc2  = (const float*)d_in[23];
  const float* bc2  = (const float*)d_in[24];

  const int* srcs = ei;
  const int* dsts = ei + N_EDGES;

  float* ws = (float*)d_ws;
  size_t o = 0;
  ushort* XLB = (ushort*)(ws + o); o += (size_t)N_NODES * HIDD / 2;  // bf16 xl
  float* XR = ws + o;            o += (size_t)N_NODES * HIDD;
  float* Hb = ws + o;            o += (size_t)N_NODES * HIDD;
  ushort* AH = (ushort*)(ws + o); o += (size_t)N_NODES * HIDD / 2;
  ushort* AL = (ushort*)(ws + o); o += (size_t)N_NODES * HIDD / 2;
  ushort* BT2 = (ushort*)(ws + o); o += (size_t)4 * 32 * 256 * 8 / 2;   // 2 mats x 2 halves
  ushort* BT3 = (ushort*)(ws + o); o += (size_t)4 * 32 * 64 * 8 / 2;
  int* ESRC = (int*)(ws + o);    o += ET;
  int* ROWS = (int*)(ws + o);    o += N_NODES + 1;
  int* CURS = (int*)(ws + o);    o += N_NODES;
  float* GS  = ws + o;           o += 256;
  float* GSQ = ws + o;           o += 256;
  float* SC  = ws + o;           o += 256;
  float* SH  = ws + o;           o += 256;

  const int ROW_BLOCKS = (N_NODES + 63) / 64;
  const int DST_BLOCKS = (N_NODES + 3) / 4;
  const int A4 = N_NODES * HIDD / 4;
  constexpr int PLANE2 = 32 * 256 * 8;
  constexpr int PLANE3 = 32 * 64 * 8;

  // ================= weight transpose/split (independent; run once up front)
  convertB<256, 256><<<(65536 + 255) / 256, 256, 0, stream>>>(Wl2, BT2);
  convertB<256, 256><<<(65536 + 255) / 256, 256, 0, stream>>>(Wr2, BT2 + 2 * PLANE2);
  convertB<256, 64><<<(16384 + 255) / 256, 256, 0, stream>>>(Wl3, BT3);
  convertB<256, 64><<<(16384 + 255) / 256, 256, 0, stream>>>(Wr3, BT3 + 2 * PLANE3);

  // ================= CSR build (reused by all 3 layers) =================
  hipMemsetAsync(CURS, 0, N_NODES * 4, stream);
  hist_kernel<<<(ET + 255) / 256, 256, 0, stream>>>(dsts, CURS);
  scan_kernel<<<1, 1024, 0, stream>>>(CURS, ROWS);
  scatter_kernel<<<(ET + 255) / 256, 256, 0, stream>>>(srcs, dsts, CURS, ESRC);

  // ================= layer 1 (16 -> 4x64, concat): fp32 vector GEMM ======
  gemm_dual<16, 256><<<dim3(ROW_BLOCKS, 4), 256, 0, stream>>>(
      x, Wl1, Wr1, XLB, XR, N_NODES);
  flash_csr<4, 256><<<DST_BLOCKS, 256, 0, stream>>>(XLB, XR, att1, ROWS, ESRC, Hb);
  hipMemsetAsync(GS, 0, 512 * 4, stream);
  bn_stats<256, 64><<<ROW_BLOCKS, 256, 0, stream>>>(Hb, GS, GSQ, N_NODES);
  bn_finalize<<<1, 256, 0, stream>>>(GS, GSQ, g1, be1, SC, SH, 256);

  // ================= layer 2 (256 -> 4x64): BN+ELU fused convert, MFMA GEMM
  convertA<<<(A4 + 255) / 256, 256, 0, stream>>>(Hb, SC, SH, AH, AL, A4);
  gemm_mfma_dual<256><<<dim3(ROW_BLOCKS, 4), 256, 0, stream>>>(AH, AL, BT2, XLB, XR);
  flash_csr<4, 256><<<DST_BLOCKS, 256, 0, stream>>>(XLB, XR, att2, ROWS, ESRC, Hb);
  hipMemsetAsync(GS, 0, 512 * 4, stream);
  bn_stats<256, 64><<<ROW_BLOCKS, 256, 0, stream>>>(Hb, GS, GSQ, N_NODES);
  bn_finalize<<<1, 256, 0, stream>>>(GS, GSQ, g2, be2, SC, SH, 256);

  // ================= layer 3 (256 -> 64, 1 head): MFMA GEMM ==============
  convertA<<<(A4 + 255) / 256, 256, 0, stream>>>(Hb, SC, SH, AH, AL, A4);
  gemm_mfma_dual<64><<<dim3(ROW_BLOCKS, 1), 256, 0, stream>>>(AH, AL, BT3, XLB, XR);
  flash_csr<1, 64><<<DST_BLOCKS, 256, 0, stream>>>(XLB, XR, att3, ROWS, ESRC, Hb);
  hipMemsetAsync(GS, 0, 512 * 4, stream);
  bn_stats<64, 256><<<(N_NODES + 255) / 256, 256, 0, stream>>>(Hb, GS, GSQ, N_NODES);
  bn_finalize<<<1, 64, 0, stream>>>(GS, GSQ, g3, be3, SC, SH, 64);

  // ================= fused pooling (BN inline) + classifier ==============
  pool_mlp<<<N_GRAPHS, 256, 0, stream>>>(Hb, batch, SC, SH, Wc1, bc1, Wc2, bc2,
                                         (float*)d_out);
}

// Round 6
// 647.553 us; speedup vs baseline: 11.0861x; 1.1972x over previous
//
#include <hip/hip_runtime.h>
#include <math.h>

#define N_NODES 50000
#define N_EDGES 800000
#define ET (N_EDGES + N_NODES)
#define N_GRAPHS 200
#define F_INN 16
#define C_DIM 64
#define N_HEADS 4
#define HIDD 256
#define SCAN_BLOCKS ((N_NODES + 255) / 256)

typedef __attribute__((ext_vector_type(8))) short short8;
typedef __attribute__((ext_vector_type(4))) float f32x4;

__device__ __forceinline__ float bf2f(ushort u) {
  return __uint_as_float(((unsigned)u) << 16);
}
__device__ __forceinline__ ushort f2bf(float f) {  // round-to-nearest-even
  unsigned u = __float_as_uint(f);
  u += 0x7fff + ((u >> 16) & 1);
  return (ushort)(u >> 16);
}

// ---------------- dual GEMM (fp32 vector path, layer 1 only: K=16)
// Cl written as bf16 (feeds edge gathers), Cr as fp32.
template<int K, int M>
__global__ __launch_bounds__(256) void gemm_dual(
    const float* __restrict__ A, const float* __restrict__ Bl,
    const float* __restrict__ Br, ushort* __restrict__ Clb,
    float* __restrict__ Cr, int nrows)
{
  __shared__ __align__(16) float As[16][64];
  __shared__ __align__(16) float Bls[16][64];
  __shared__ __align__(16) float Brs[16][64];
  int tid = threadIdx.x;
  int row0 = blockIdx.x * 64;
  int col0 = blockIdx.y * 64;
  int tr = (tid >> 4) << 2;
  int tc = (tid & 15) << 2;
  float accL[4][4] = {{0.f}}, accR[4][4] = {{0.f}};
  int arow = tid >> 2, ak = (tid & 3) << 2;
  int brow = tid >> 4, bcol = (tid & 15) << 2;
  for (int k0 = 0; k0 < K; k0 += 16) {
    float4 av = make_float4(0.f, 0.f, 0.f, 0.f);
    int gr = row0 + arow;
    if (gr < nrows) av = *(const float4*)&A[(size_t)gr * K + k0 + ak];
    As[ak + 0][arow] = av.x;
    As[ak + 1][arow] = av.y;
    As[ak + 2][arow] = av.z;
    As[ak + 3][arow] = av.w;
    *(float4*)&Bls[brow][bcol] = *(const float4*)&Bl[(size_t)(k0 + brow) * M + col0 + bcol];
    *(float4*)&Brs[brow][bcol] = *(const float4*)&Br[(size_t)(k0 + brow) * M + col0 + bcol];
    __syncthreads();
    #pragma unroll
    for (int k = 0; k < 16; ++k) {
      float4 a = *(const float4*)&As[k][tr];
      float4 bl = *(const float4*)&Bls[k][tc];
      float4 br = *(const float4*)&Brs[k][tc];
      float aa[4] = {a.x, a.y, a.z, a.w};
      float lb[4] = {bl.x, bl.y, bl.z, bl.w};
      float rb[4] = {br.x, br.y, br.z, br.w};
      #pragma unroll
      for (int ii = 0; ii < 4; ++ii)
        #pragma unroll
        for (int jj = 0; jj < 4; ++jj) {
          accL[ii][jj] = fmaf(aa[ii], lb[jj], accL[ii][jj]);
          accR[ii][jj] = fmaf(aa[ii], rb[jj], accR[ii][jj]);
        }
    }
    __syncthreads();
  }
  #pragma unroll
  for (int ii = 0; ii < 4; ++ii) {
    int gr = row0 + tr + ii;
    if (gr < nrows) {
      *(ushort4*)&Clb[(size_t)gr * M + col0 + tc] =
          make_ushort4(f2bf(accL[ii][0]), f2bf(accL[ii][1]),
                       f2bf(accL[ii][2]), f2bf(accL[ii][3]));
      *(float4*)&Cr[(size_t)gr * M + col0 + tc] =
          make_float4(accR[ii][0], accR[ii][1], accR[ii][2], accR[ii][3]);
    }
  }
}

// ---------------- bf16x2 split helpers
__device__ __forceinline__ void split_bf16(float a, ushort& hi, ushort& lo) {
  unsigned u = __float_as_uint(a);
  hi = (ushort)(u >> 16);
  float ah = __uint_as_float(u & 0xffff0000u);
  float r = a - ah;                      // exact
  lo = (ushort)(__float_as_uint(r) >> 16);
}

// ---------------- convert activations: h' = elu(bn(h)) -> bf16 hi/lo planes
// BN finalize folded in: scale/shift computed per-thread from gsum/gsumsq/g/be.
__global__ __launch_bounds__(256) void convertA(
    const float* __restrict__ H, const float* __restrict__ gsum,
    const float* __restrict__ gsumsq, const float* __restrict__ g,
    const float* __restrict__ be, ushort* __restrict__ Ah,
    ushort* __restrict__ Al, int total4)
{
  int idx = blockIdx.x * blockDim.x + threadIdx.x;
  if (idx >= total4) return;
  int c0 = (idx * 4) & 255;
  float4 v = *(const float4*)&H[(size_t)idx * 4];
  float4 gs4 = *(const float4*)&gsum[c0];
  float4 gq4 = *(const float4*)&gsumsq[c0];
  float4 gg4 = *(const float4*)&g[c0];
  float4 bb4 = *(const float4*)&be[c0];
  const float invn = 1.0f / (float)N_NODES;
  float sc[4], sh[4];
  {
    float gs[4] = {gs4.x, gs4.y, gs4.z, gs4.w};
    float gq[4] = {gq4.x, gq4.y, gq4.z, gq4.w};
    float gg[4] = {gg4.x, gg4.y, gg4.z, gg4.w};
    float bb[4] = {bb4.x, bb4.y, bb4.z, bb4.w};
    #pragma unroll
    for (int j = 0; j < 4; ++j) {
      float mu = gs[j] * invn;
      float var = gq[j] * invn - mu * mu;
      sc[j] = gg[j] * rsqrtf(var + 1e-5f);
      sh[j] = bb[j] - mu * sc[j];
    }
  }
  float t[4] = {fmaf(v.x, sc[0], sh[0]), fmaf(v.y, sc[1], sh[1]),
                fmaf(v.z, sc[2], sh[2]), fmaf(v.w, sc[3], sh[3])};
  ushort hi[4], lo[4];
  #pragma unroll
  for (int j = 0; j < 4; ++j) {
    float e = t[j] > 0.f ? t[j] : __expf(t[j]) - 1.f;
    split_bf16(e, hi[j], lo[j]);
  }
  *(ushort4*)&Ah[(size_t)idx * 4] = make_ushort4(hi[0], hi[1], hi[2], hi[3]);
  *(ushort4*)&Al[(size_t)idx * 4] = make_ushort4(lo[0], lo[1], lo[2], lo[3]);
}

// ---------------- convert a weight matrix [K][N] -> [half][K/8][N][8] bf16
template<int K, int N>
__global__ void convertB(const float* __restrict__ W, ushort* __restrict__ BTmat) {
  int idx = blockIdx.x * blockDim.x + threadIdx.x;
  if (idx >= K * N) return;
  int k = idx / N, n = idx - k * N;
  ushort hi, lo;
  split_bf16(W[idx], hi, lo);
  size_t dst = ((size_t)(k >> 3) * N + n) * 8 + (k & 7);
  BTmat[dst] = hi;
  BTmat[(size_t)(K / 8) * N * 8 + dst] = lo;
}

// ---------------- MFMA dual GEMM: Cl = A@Bl (bf16 out), Cr = A@Br (fp32 out)
// A: [M][256] bf16 hi/lo planes. BT: [mat][half][K/8][N][8]. No LDS, no barriers.
template<int N>
__global__ __launch_bounds__(256) void gemm_mfma_dual(
    const ushort* __restrict__ Ah, const ushort* __restrict__ Al,
    const ushort* __restrict__ BT, ushort* __restrict__ Clb,
    float* __restrict__ Cr)
{
  constexpr int K = 256;
  constexpr int PLANE = (K / 8) * N * 8;
  const int wave = threadIdx.x >> 6;
  const int lane = threadIdx.x & 63;
  const int r0 = blockIdx.x * 64 + wave * 16;
  const int col0 = blockIdx.y * 64;
  const int kgrp = lane >> 4;      // 0..3
  const int cn = lane & 15;
  const int arow = min(r0 + cn, N_NODES - 1);
  const size_t abase = (size_t)arow * K;
  const ushort* Blh = BT;
  const ushort* Bll = BT + PLANE;
  const ushort* Brh = BT + 2 * PLANE;
  const ushort* Brl = BT + 3 * PLANE;
  f32x4 accL[4], accR[4];
  #pragma unroll
  for (int t = 0; t < 4; ++t) {
    accL[t] = (f32x4)(0.f);
    accR[t] = (f32x4)(0.f);
  }
  #pragma unroll 2
  for (int k0 = 0; k0 < K; k0 += 32) {
    short8 a_h = *(const short8*)&Ah[abase + k0 + kgrp * 8];
    short8 a_l = *(const short8*)&Al[abase + k0 + kgrp * 8];
    const size_t boff = ((size_t)(k0 >> 3) + kgrp) * (N * 8) + (size_t)cn * 8;
    #pragma unroll
    for (int t = 0; t < 4; ++t) {
      const size_t bo = boff + (size_t)(col0 + 16 * t) * 8;
      short8 blh = *(const short8*)&Blh[bo];
      short8 bll = *(const short8*)&Bll[bo];
      short8 brh = *(const short8*)&Brh[bo];
      short8 brl = *(const short8*)&Brl[bo];
      accL[t] = __builtin_amdgcn_mfma_f32_16x16x32_bf16(a_h, blh, accL[t], 0, 0, 0);
      accL[t] = __builtin_amdgcn_mfma_f32_16x16x32_bf16(a_h, bll, accL[t], 0, 0, 0);
      accL[t] = __builtin_amdgcn_mfma_f32_16x16x32_bf16(a_l, blh, accL[t], 0, 0, 0);
      accR[t] = __builtin_amdgcn_mfma_f32_16x16x32_bf16(a_h, brh, accR[t], 0, 0, 0);
      accR[t] = __builtin_amdgcn_mfma_f32_16x16x32_bf16(a_h, brl, accR[t], 0, 0, 0);
      accR[t] = __builtin_amdgcn_mfma_f32_16x16x32_bf16(a_l, brh, accR[t], 0, 0, 0);
    }
  }
  // C/D layout: col = lane&15, row = (lane>>4)*4 + reg   [m89 verified]
  const int crow0 = r0 + kgrp * 4;
  #pragma unroll
  for (int t = 0; t < 4; ++t) {
    int cc = col0 + 16 * t + cn;
    #pragma unroll
    for (int j = 0; j < 4; ++j) {
      int rr = crow0 + j;
      if (rr < N_NODES) {
        Clb[(size_t)rr * N + cc] = f2bf(accL[t][j]);
        Cr[(size_t)rr * N + cc] = accR[t][j];
      }
    }
  }
}

// ---------------- CSR build: histogram -> multi-block scan -> scatter
__global__ void hist_kernel(const int* __restrict__ dsts, int* __restrict__ curs) {
  int i = blockIdx.x * blockDim.x + threadIdx.x;
  if (i >= ET) return;
  int d = (i < N_EDGES) ? dsts[i] : i - N_EDGES;
  atomicAdd(&curs[d], 1);
}

// per-block exclusive scan of degrees; writes within-block exclusive to rows,
// block total to bsum.
__global__ __launch_bounds__(256) void scan_part(
    const int* __restrict__ curs, int* __restrict__ rows, int* __restrict__ bsum)
{
  __shared__ int tmp[256];
  int t = threadIdx.x;
  int i = blockIdx.x * 256 + t;
  int v = (i < N_NODES) ? curs[i] : 0;
  tmp[t] = v;
  __syncthreads();
  #pragma unroll
  for (int off = 1; off < 256; off <<= 1) {
    int u = (t >= off) ? tmp[t - off] : 0;
    __syncthreads();
    tmp[t] += u;
    __syncthreads();
  }
  if (i < N_NODES) rows[i] = tmp[t] - v;   // exclusive within block
  if (t == 255) bsum[blockIdx.x] = tmp[255];
}

// single small block: exclusive scan of the 196 block sums.
__global__ __launch_bounds__(256) void scan_bsums(
    const int* __restrict__ bsum, int* __restrict__ boff)
{
  __shared__ int tmp[256];
  int t = threadIdx.x;
  int v = (t < SCAN_BLOCKS) ? bsum[t] : 0;
  tmp[t] = v;
  __syncthreads();
  #pragma unroll
  for (int off = 1; off < 256; off <<= 1) {
    int u = (t >= off) ? tmp[t - off] : 0;
    __syncthreads();
    tmp[t] += u;
    __syncthreads();
  }
  if (t < SCAN_BLOCKS) boff[t] = tmp[t] - v;
}

// add block offsets; fill curs (= row starts) for the scatter pass.
__global__ __launch_bounds__(256) void scan_apply(
    int* __restrict__ rows, const int* __restrict__ boff, int* __restrict__ curs)
{
  int i = blockIdx.x * 256 + threadIdx.x;
  if (i < N_NODES) {
    int r = rows[i] + boff[blockIdx.x];
    rows[i] = r;
    curs[i] = r;
  }
  if (i == 0) rows[N_NODES] = ET;  // total degree is compile-time constant
}

__global__ void scatter_kernel(const int* __restrict__ srcs, const int* __restrict__ dsts,
                               int* __restrict__ curs, int* __restrict__ esrc) {
  int i = blockIdx.x * blockDim.x + threadIdx.x;
  if (i >= ET) return;
  int s, d;
  if (i < N_EDGES) { s = srcs[i]; d = dsts[i]; } else { s = d = i - N_EDGES; }
  int pos = atomicAdd(&curs[d], 1);
  esrc[pos] = s;
}

// ---------------- fused flash-attention pass: one wave per dst, online softmax,
// bf16 xl gathers, fp32 xr, 4 edges/iter (D=256), register accumulator.
template<int HEADS_, int D_>
__global__ __launch_bounds__(256) void flash_csr(
    const ushort* __restrict__ xl, const float* __restrict__ xr,
    const float* __restrict__ att, const int* __restrict__ rows,
    const int* __restrict__ esrc, float* __restrict__ out)
{
  int d = blockIdx.x * 4 + (threadIdx.x >> 6);
  if (d >= N_NODES) return;
  int lane = threadIdx.x & 63;
  int beg = rows[d], end = rows[d + 1];
  if constexpr (D_ == 256) {
    float4 xrv = *(const float4*)&xr[(size_t)d * 256 + lane * 4];
    float4 w = *(const float4*)&att[lane * 4];
    auto score = [&](float b0, float b1, float b2, float b3) {
      float v0 = b0 + xrv.x, v1 = b1 + xrv.y, v2 = b2 + xrv.z, v3 = b3 + xrv.w;
      v0 = v0 > 0.f ? v0 : 0.2f * v0;
      v1 = v1 > 0.f ? v1 : 0.2f * v1;
      v2 = v2 > 0.f ? v2 : 0.2f * v2;
      v3 = v3 > 0.f ? v3 : 0.2f * v3;
      return fmaf(v0, w.x, fmaf(v1, w.y, fmaf(v2, w.z, v3 * w.w)));
    };
    float m = -INFINITY, s = 0.f;
    float a0 = 0.f, a1 = 0.f, a2 = 0.f, a3 = 0.f;
    int p = beg;
    for (; p + 4 <= end; p += 4) {
      int s1 = esrc[p], s2 = esrc[p + 1], s3 = esrc[p + 2], s4 = esrc[p + 3];
      ushort4 u1 = *(const ushort4*)&xl[(size_t)s1 * 256 + lane * 4];
      ushort4 u2 = *(const ushort4*)&xl[(size_t)s2 * 256 + lane * 4];
      ushort4 u3 = *(const ushort4*)&xl[(size_t)s3 * 256 + lane * 4];
      ushort4 u4 = *(const ushort4*)&xl[(size_t)s4 * 256 + lane * 4];
      float b10 = bf2f(u1.x), b11 = bf2f(u1.y), b12 = bf2f(u1.z), b13 = bf2f(u1.w);
      float b20 = bf2f(u2.x), b21 = bf2f(u2.y), b22 = bf2f(u2.z), b23 = bf2f(u2.w);
      float b30 = bf2f(u3.x), b31 = bf2f(u3.y), b32 = bf2f(u3.z), b33 = bf2f(u3.w);
      float b40 = bf2f(u4.x), b41 = bf2f(u4.y), b42 = bf2f(u4.z), b43 = bf2f(u4.w);
      float e1 = score(b10, b11, b12, b13);
      float e2 = score(b20, b21, b22, b23);
      float e3 = score(b30, b31, b32, b33);
      float e4 = score(b40, b41, b42, b43);
      e1 += __shfl_xor(e1, 1); e2 += __shfl_xor(e2, 1);
      e3 += __shfl_xor(e3, 1); e4 += __shfl_xor(e4, 1);
      e1 += __shfl_xor(e1, 2); e2 += __shfl_xor(e2, 2);
      e3 += __shfl_xor(e3, 2); e4 += __shfl_xor(e4, 2);
      e1 += __shfl_xor(e1, 4); e2 += __shfl_xor(e2, 4);
      e3 += __shfl_xor(e3, 4); e4 += __shfl_xor(e4, 4);
      e1 += __shfl_xor(e1, 8); e2 += __shfl_xor(e2, 8);
      e3 += __shfl_xor(e3, 8); e4 += __shfl_xor(e4, 8);
      float mn = fmaxf(fmaxf(m, fmaxf(e1, e2)), fmaxf(e3, e4));
      float f = __expf(m - mn);
      float p1 = __expf(e1 - mn);
      float p2 = __expf(e2 - mn);
      float p3 = __expf(e3 - mn);
      float p4 = __expf(e4 - mn);
      s = fmaf(s, f, (p1 + p2) + (p3 + p4));
      a0 = fmaf(a0, f, fmaf(p1, b10, fmaf(p2, b20, fmaf(p3, b30, p4 * b40))));
      a1 = fmaf(a1, f, fmaf(p1, b11, fmaf(p2, b21, fmaf(p3, b31, p4 * b41))));
      a2 = fmaf(a2, f, fmaf(p1, b12, fmaf(p2, b22, fmaf(p3, b32, p4 * b42))));
      a3 = fmaf(a3, f, fmaf(p1, b13, fmaf(p2, b23, fmaf(p3, b33, p4 * b43))));
      m = mn;
    }
    for (; p < end; ++p) {
      int s1 = esrc[p];
      ushort4 u1 = *(const ushort4*)&xl[(size_t)s1 * 256 + lane * 4];
      float b10 = bf2f(u1.x), b11 = bf2f(u1.y), b12 = bf2f(u1.z), b13 = bf2f(u1.w);
      float e1 = score(b10, b11, b12, b13);
      e1 += __shfl_xor(e1, 1);
      e1 += __shfl_xor(e1, 2);
      e1 += __shfl_xor(e1, 4);
      e1 += __shfl_xor(e1, 8);
      float mn = fmaxf(m, e1);
      float f = __expf(m - mn);
      float p1 = __expf(e1 - mn);
      s = fmaf(s, f, p1);
      a0 = fmaf(a0, f, p1 * b10);
      a1 = fmaf(a1, f, p1 * b11);
      a2 = fmaf(a2, f, p1 * b12);
      a3 = fmaf(a3, f, p1 * b13);
      m = mn;
    }
    float inv = 1.f / (s + 1e-16f);
    *(float4*)&out[(size_t)d * 256 + lane * 4] =
        make_float4(a0 * inv, a1 * inv, a2 * inv, a3 * inv);
  } else {  // 1 head, D=64
    float xrv = xr[(size_t)d * 64 + lane];
    float w = att[lane];
    float m = -INFINITY, s = 0.f, acc = 0.f;
    int p = beg;
    for (; p + 2 <= end; p += 2) {
      int s1 = esrc[p], s2 = esrc[p + 1];
      float b1 = bf2f(xl[(size_t)s1 * 64 + lane]);
      float b2 = bf2f(xl[(size_t)s2 * 64 + lane]);
      float v1 = b1 + xrv, v2 = b2 + xrv;
      v1 = v1 > 0.f ? v1 : 0.2f * v1;
      v2 = v2 > 0.f ? v2 : 0.2f * v2;
      float e1 = v1 * w, e2 = v2 * w;
      e1 += __shfl_xor(e1, 1);  e2 += __shfl_xor(e2, 1);
      e1 += __shfl_xor(e1, 2);  e2 += __shfl_xor(e2, 2);
      e1 += __shfl_xor(e1, 4);  e2 += __shfl_xor(e2, 4);
      e1 += __shfl_xor(e1, 8);  e2 += __shfl_xor(e2, 8);
      e1 += __shfl_xor(e1, 16); e2 += __shfl_xor(e2, 16);
      e1 += __shfl_xor(e1, 32); e2 += __shfl_xor(e2, 32);
      float mn = fmaxf(m, fmaxf(e1, e2));
      float f = __expf(m - mn);
      float p1 = __expf(e1 - mn);
      float p2 = __expf(e2 - mn);
      s = fmaf(s, f, p1 + p2);
      acc = fmaf(acc, f, fmaf(p1, b1, p2 * b2));
      m = mn;
    }
    if (p < end) {
      int s1 = esrc[p];
      float b1 = bf2f(xl[(size_t)s1 * 64 + lane]);
      float v1 = b1 + xrv;
      v1 = v1 > 0.f ? v1 : 0.2f * v1;
      float e1 = v1 * w;
      e1 += __shfl_xor(e1, 1);
      e1 += __shfl_xor(e1, 2);
      e1 += __shfl_xor(e1, 4);
      e1 += __shfl_xor(e1, 8);
      e1 += __shfl_xor(e1, 16);
      e1 += __shfl_xor(e1, 32);
      float mn = fmaxf(m, e1);
      float f = __expf(m - mn);
      float p1 = __expf(e1 - mn);
      s = fmaf(s, f, p1);
      acc = fmaf(acc, f, p1 * b1);
    }
    out[(size_t)d * 64 + lane] = acc / (s + 1e-16f);
  }
}

// ---------------- BN statistics (per-channel sum / sumsq)
template<int D_, int RPB>
__global__ __launch_bounds__(256) void bn_stats(const float* __restrict__ h,
    float* __restrict__ gsum, float* __restrict__ gsumsq, int nrows)
{
  constexpr int RG = 256 / D_;
  int c = threadIdx.x % D_;
  int rg = threadIdx.x / D_;
  int r0 = blockIdx.x * RPB;
  float s = 0.f, sq = 0.f;
  int rend = min(r0 + RPB, nrows);
  for (int r = r0 + rg; r < rend; r += RG) {
    float v = h[(size_t)r * D_ + c];
    s += v;
    sq = fmaf(v, v, sq);
  }
  atomicAdd(&gsum[c], s);
  atomicAdd(&gsumsq[c], sq);
}

// ---------------- fused pooling (BN finalize+apply inline) + classifier MLP.
__global__ __launch_bounds__(256) void pool_mlp(
    const float* __restrict__ h3, const int* __restrict__ batch,
    const float* __restrict__ gsum, const float* __restrict__ gsumsq,
    const float* __restrict__ g3, const float* __restrict__ be3,
    const float* __restrict__ Wc1, const float* __restrict__ bc1,
    const float* __restrict__ Wc2, const float* __restrict__ bc2,
    float* __restrict__ outp)
{
  int g = blockIdx.x;
  int t = threadIdx.x;
  int lane = t & 63, w = t >> 6;
  int lo, hi;
  {
    int a = 0, b = N_NODES;
    while (a < b) { int mid = (a + b) >> 1; if (batch[mid] < g) a = mid + 1; else b = mid; }
    lo = a;
    b = N_NODES;
    while (a < b) { int mid = (a + b) >> 1; if (batch[mid] < g + 1) a = mid + 1; else b = mid; }
    hi = a;
  }
  const float invn = 1.0f / (float)N_NODES;
  float mu = gsum[lane] * invn;
  float var = gsumsq[lane] * invn - mu * mu;
  float scl = g3[lane] * rsqrtf(var + 1e-5f);
  float shf = be3[lane] - mu * scl;
  float s = 0.f, mx = -INFINITY;
  for (int r = lo + w; r < hi; r += 4) {
    float v = fmaf(h3[(size_t)r * 64 + lane], scl, shf);
    s += v;
    mx = fmaxf(mx, v);
  }
  __shared__ float ssum[4][64];
  __shared__ float smax[4][64];
  __shared__ float pooled[128];
  ssum[w][lane] = s;
  smax[w][lane] = mx;
  __syncthreads();
  if (w == 0) {
    float tot = ssum[0][lane] + ssum[1][lane] + ssum[2][lane] + ssum[3][lane];
    float m4 = fmaxf(fmaxf(smax[0][lane], smax[1][lane]),
                     fmaxf(smax[2][lane], smax[3][lane]));
    float cnt = (float)(hi - lo);
    pooled[lane] = tot / fmaxf(cnt, 1.f);
    pooled[64 + lane] = m4;
  }
  __syncthreads();
  if (w == 0) {
    float a = bc1[lane];
    #pragma unroll 8
    for (int k = 0; k < 128; ++k) a = fmaf(pooled[k], Wc1[k * 64 + lane], a);
    a = fmaxf(a, 0.f);
    float v = a * Wc2[lane];
    v += __shfl_xor(v, 1);
    v += __shfl_xor(v, 2);
    v += __shfl_xor(v, 4);
    v += __shfl_xor(v, 8);
    v += __shfl_xor(v, 16);
    v += __shfl_xor(v, 32);
    if (lane == 0) outp[g] = v + bc2[0];
  }
}

extern "C" void kernel_launch(void* const* d_in, const int* in_sizes, int n_in,
                              void* d_out, int out_size, void* d_ws, size_t ws_size,
                              hipStream_t stream)
{
  const float* x    = (const float*)d_in[0];
  const int*   ei   = (const int*)d_in[1];
  const int*   batch= (const int*)d_in[2];
  const float* Wl1  = (const float*)d_in[3];
  const float* Wr1  = (const float*)d_in[4];
  const float* att1 = (const float*)d_in[5];
  // b1/b2/b3 cancel in the following BatchNorm -> unused
  const float* g1   = (const float*)d_in[7];
  const float* be1  = (const float*)d_in[8];
  const float* Wl2  = (const float*)d_in[9];
  const float* Wr2  = (const float*)d_in[10];
  const float* att2 = (const float*)d_in[11];
  const float* g2   = (const float*)d_in[13];
  const float* be2  = (const float*)d_in[14];
  const float* Wl3  = (const float*)d_in[15];
  const float* Wr3  = (const float*)d_in[16];
  const float* att3 = (const float*)d_in[17];
  const float* g3   = (const float*)d_in[19];
  const float* be3  = (const float*)d_in[20];
  const float* Wc1  = (const float*)d_in[21];
  const float* bc1  = (const float*)d_in[22];
  const float* Wc2  = (const float*)d_in[23];
  const float* bc2  = (const float*)d_in[24];

  const int* srcs = ei;
  const int* dsts = ei + N_EDGES;

  float* ws = (float*)d_ws;
  size_t o = 0;
  ushort* XLB = (ushort*)(ws + o); o += (size_t)N_NODES * HIDD / 2;  // bf16 xl
  float* XR = ws + o;            o += (size_t)N_NODES * HIDD;
  float* Hb = ws + o;            o += (size_t)N_NODES * HIDD;
  ushort* AH = (ushort*)(ws + o); o += (size_t)N_NODES * HIDD / 2;
  ushort* AL = (ushort*)(ws + o); o += (size_t)N_NODES * HIDD / 2;
  ushort* BT2 = (ushort*)(ws + o); o += (size_t)4 * 32 * 256 * 8 / 2;   // 2 mats x 2 halves
  ushort* BT3 = (ushort*)(ws + o); o += (size_t)4 * 32 * 64 * 8 / 2;
  int* ESRC = (int*)(ws + o);    o += ET;
  int* ROWS = (int*)(ws + o);    o += N_NODES + 1;
  int* CURS = (int*)(ws + o);    o += N_NODES;
  int* BSUM = (int*)(ws + o);    o += SCAN_BLOCKS;
  int* BOFF = (int*)(ws + o);    o += SCAN_BLOCKS;
  float* GS  = ws + o;           o += 256;
  float* GSQ = ws + o;           o += 256;

  const int ROW_BLOCKS = (N_NODES + 63) / 64;
  const int DST_BLOCKS = (N_NODES + 3) / 4;
  const int A4 = N_NODES * HIDD / 4;
  constexpr int PLANE2 = 32 * 256 * 8;
  constexpr int PLANE3 = 32 * 64 * 8;

  // ================= weight transpose/split (independent; run once up front)
  convertB<256, 256><<<(65536 + 255) / 256, 256, 0, stream>>>(Wl2, BT2);
  convertB<256, 256><<<(65536 + 255) / 256, 256, 0, stream>>>(Wr2, BT2 + 2 * PLANE2);
  convertB<256, 64><<<(16384 + 255) / 256, 256, 0, stream>>>(Wl3, BT3);
  convertB<256, 64><<<(16384 + 255) / 256, 256, 0, stream>>>(Wr3, BT3 + 2 * PLANE3);

  // ================= CSR build (reused by all 3 layers) =================
  hipMemsetAsync(CURS, 0, N_NODES * 4, stream);
  hist_kernel<<<(ET + 255) / 256, 256, 0, stream>>>(dsts, CURS);
  scan_part<<<SCAN_BLOCKS, 256, 0, stream>>>(CURS, ROWS, BSUM);
  scan_bsums<<<1, 256, 0, stream>>>(BSUM, BOFF);
  scan_apply<<<SCAN_BLOCKS, 256, 0, stream>>>(ROWS, BOFF, CURS);
  scatter_kernel<<<(ET + 255) / 256, 256, 0, stream>>>(srcs, dsts, CURS, ESRC);

  // ================= layer 1 (16 -> 4x64, concat): fp32 vector GEMM ======
  gemm_dual<16, 256><<<dim3(ROW_BLOCKS, 4), 256, 0, stream>>>(
      x, Wl1, Wr1, XLB, XR, N_NODES);
  flash_csr<4, 256><<<DST_BLOCKS, 256, 0, stream>>>(XLB, XR, att1, ROWS, ESRC, Hb);
  hipMemsetAsync(GS, 0, 512 * 4, stream);
  bn_stats<256, 64><<<ROW_BLOCKS, 256, 0, stream>>>(Hb, GS, GSQ, N_NODES);

  // ================= layer 2 (256 -> 4x64): BN+ELU fused convert, MFMA GEMM
  convertA<<<(A4 + 255) / 256, 256, 0, stream>>>(Hb, GS, GSQ, g1, be1, AH, AL, A4);
  gemm_mfma_dual<256><<<dim3(ROW_BLOCKS, 4), 256, 0, stream>>>(AH, AL, BT2, XLB, XR);
  flash_csr<4, 256><<<DST_BLOCKS, 256, 0, stream>>>(XLB, XR, att2, ROWS, ESRC, Hb);
  hipMemsetAsync(GS, 0, 512 * 4, stream);
  bn_stats<256, 64><<<ROW_BLOCKS, 256, 0, stream>>>(Hb, GS, GSQ, N_NODES);

  // ================= layer 3 (256 -> 64, 1 head): MFMA GEMM ==============
  convertA<<<(A4 + 255) / 256, 256, 0, stream>>>(Hb, GS, GSQ, g2, be2, AH, AL, A4);
  gemm_mfma_dual<64><<<dim3(ROW_BLOCKS, 1), 256, 0, stream>>>(AH, AL, BT3, XLB, XR);
  flash_csr<1, 64><<<DST_BLOCKS, 256, 0, stream>>>(XLB, XR, att3, ROWS, ESRC, Hb);
  hipMemsetAsync(GS, 0, 512 * 4, stream);
  bn_stats<64, 256><<<(N_NODES + 255) / 256, 256, 0, stream>>>(Hb, GS, GSQ, N_NODES);

  // ================= fused pooling (BN inline) + classifier ==============
  pool_mlp<<<N_GRAPHS, 256, 0, stream>>>(Hb, batch, GS, GSQ, g3, be3,
                                         Wc1, bc1, Wc2, bc2, (float*)d_out);
}

// Round 7
// 598.636 us; speedup vs baseline: 11.9920x; 1.0817x over previous
//
#include <hip/hip_runtime.h>
#include <math.h>

#define N_NODES 50000
#define N_EDGES 800000
#define ET (N_EDGES + N_NODES)
#define N_GRAPHS 200
#define F_INN 16
#define C_DIM 64
#define N_HEADS 4
#define HIDD 256
#define SCAN_BLOCKS ((N_NODES + 255) / 256)

typedef __attribute__((ext_vector_type(8))) short short8;
typedef __attribute__((ext_vector_type(4))) float f32x4;

__device__ __forceinline__ float bf2f(ushort u) {
  return __uint_as_float(((unsigned)u) << 16);
}
__device__ __forceinline__ ushort f2bf(float f) {  // round-to-nearest-even
  unsigned u = __float_as_uint(f);
  u += 0x7fff + ((u >> 16) & 1);
  return (ushort)(u >> 16);
}

// ---------------- dual GEMM (fp32 vector path, layer 1 only: K=16)
// Cl written as bf16 (feeds edge gathers), Cr as fp32.
template<int K, int M>
__global__ __launch_bounds__(256) void gemm_dual(
    const float* __restrict__ A, const float* __restrict__ Bl,
    const float* __restrict__ Br, ushort* __restrict__ Clb,
    float* __restrict__ Cr, int nrows)
{
  __shared__ __align__(16) float As[16][64];
  __shared__ __align__(16) float Bls[16][64];
  __shared__ __align__(16) float Brs[16][64];
  int tid = threadIdx.x;
  int row0 = blockIdx.x * 64;
  int col0 = blockIdx.y * 64;
  int tr = (tid >> 4) << 2;
  int tc = (tid & 15) << 2;
  float accL[4][4] = {{0.f}}, accR[4][4] = {{0.f}};
  int arow = tid >> 2, ak = (tid & 3) << 2;
  int brow = tid >> 4, bcol = (tid & 15) << 2;
  for (int k0 = 0; k0 < K; k0 += 16) {
    float4 av = make_float4(0.f, 0.f, 0.f, 0.f);
    int gr = row0 + arow;
    if (gr < nrows) av = *(const float4*)&A[(size_t)gr * K + k0 + ak];
    As[ak + 0][arow] = av.x;
    As[ak + 1][arow] = av.y;
    As[ak + 2][arow] = av.z;
    As[ak + 3][arow] = av.w;
    *(float4*)&Bls[brow][bcol] = *(const float4*)&Bl[(size_t)(k0 + brow) * M + col0 + bcol];
    *(float4*)&Brs[brow][bcol] = *(const float4*)&Br[(size_t)(k0 + brow) * M + col0 + bcol];
    __syncthreads();
    #pragma unroll
    for (int k = 0; k < 16; ++k) {
      float4 a = *(const float4*)&As[k][tr];
      float4 bl = *(const float4*)&Bls[k][tc];
      float4 br = *(const float4*)&Brs[k][tc];
      float aa[4] = {a.x, a.y, a.z, a.w};
      float lb[4] = {bl.x, bl.y, bl.z, bl.w};
      float rb[4] = {br.x, br.y, br.z, br.w};
      #pragma unroll
      for (int ii = 0; ii < 4; ++ii)
        #pragma unroll
        for (int jj = 0; jj < 4; ++jj) {
          accL[ii][jj] = fmaf(aa[ii], lb[jj], accL[ii][jj]);
          accR[ii][jj] = fmaf(aa[ii], rb[jj], accR[ii][jj]);
        }
    }
    __syncthreads();
  }
  #pragma unroll
  for (int ii = 0; ii < 4; ++ii) {
    int gr = row0 + tr + ii;
    if (gr < nrows) {
      *(ushort4*)&Clb[(size_t)gr * M + col0 + tc] =
          make_ushort4(f2bf(accL[ii][0]), f2bf(accL[ii][1]),
                       f2bf(accL[ii][2]), f2bf(accL[ii][3]));
      *(float4*)&Cr[(size_t)gr * M + col0 + tc] =
          make_float4(accR[ii][0], accR[ii][1], accR[ii][2], accR[ii][3]);
    }
  }
}

// ---------------- bf16x2 split helpers
__device__ __forceinline__ void split_bf16(float a, ushort& hi, ushort& lo) {
  unsigned u = __float_as_uint(a);
  hi = (ushort)(u >> 16);
  float ah = __uint_as_float(u & 0xffff0000u);
  float r = a - ah;                      // exact
  lo = (ushort)(__float_as_uint(r) >> 16);
}

// ---------------- convert a weight matrix [K][N] -> [half][K/8][N][8] bf16
template<int K, int N>
__global__ void convertB(const float* __restrict__ W, ushort* __restrict__ BTmat) {
  int idx = blockIdx.x * blockDim.x + threadIdx.x;
  if (idx >= K * N) return;
  int k = idx / N, n = idx - k * N;
  ushort hi, lo;
  split_bf16(W[idx], hi, lo);
  size_t dst = ((size_t)(k >> 3) * N + n) * 8 + (k & 7);
  BTmat[dst] = hi;
  BTmat[(size_t)(K / 8) * N * 8 + dst] = lo;
}

// ---------------- fully-fused MFMA dual GEMM (K=256):
//   A' = elu(bn(H)) split to bf16 hi/lo, staged in LDS (swizzled), read once.
//   Block covers 64 rows x ALL 2N combined cols; wave w owns 64 combined cols.
//   Cl = A'@Bl written bf16; Cr = A'@Br written fp32.
template<int N>
__global__ __launch_bounds__(N * 2) void gemm_fused(
    const float* __restrict__ H, const float* __restrict__ gsum,
    const float* __restrict__ gsumsq, const float* __restrict__ g,
    const float* __restrict__ be, const ushort* __restrict__ BT,
    ushort* __restrict__ Clb, float* __restrict__ Cr)
{
  constexpr int THREADS = N * 2;
  constexpr int PLANE = 32 * N * 8;
  __shared__ float SCs[256], SHs[256];
  __shared__ ushort Ah_s[64 * 256];
  __shared__ ushort Al_s[64 * 256];
  const int tid = threadIdx.x;
  const int brow0 = blockIdx.x * 64;

  // phase 0: BN finalize in-block
  const float invn = 1.0f / (float)N_NODES;
  for (int c = tid; c < 256; c += THREADS) {
    float mu = gsum[c] * invn;
    float var = gsumsq[c] * invn - mu * mu;
    float sc = g[c] * rsqrtf(var + 1e-5f);
    SCs[c] = sc;
    SHs[c] = be[c] - mu * sc;
  }
  __syncthreads();

  // phase 1: stage A tile -> LDS, applying BN+ELU+bf16x2 split; XOR swizzle.
  for (int gid = tid; gid < 2048; gid += THREADS) {
    int r = gid >> 5;
    int ch0 = (gid & 31) * 8;
    int grow = min(brow0 + r, N_NODES - 1);
    float4 v0 = *(const float4*)&H[(size_t)grow * 256 + ch0];
    float4 v1 = *(const float4*)&H[(size_t)grow * 256 + ch0 + 4];
    float4 sc0 = *(const float4*)&SCs[ch0];
    float4 sc1 = *(const float4*)&SCs[ch0 + 4];
    float4 sh0 = *(const float4*)&SHs[ch0];
    float4 sh1 = *(const float4*)&SHs[ch0 + 4];
    float vv[8] = {v0.x, v0.y, v0.z, v0.w, v1.x, v1.y, v1.z, v1.w};
    float scv[8] = {sc0.x, sc0.y, sc0.z, sc0.w, sc1.x, sc1.y, sc1.z, sc1.w};
    float shv[8] = {sh0.x, sh0.y, sh0.z, sh0.w, sh1.x, sh1.y, sh1.z, sh1.w};
    short8 hi8, lo8;
    #pragma unroll
    for (int j = 0; j < 8; ++j) {
      float t = fmaf(vv[j], scv[j], shv[j]);
      float e = t > 0.f ? t : __expf(t) - 1.f;
      ushort h, l;
      split_bf16(e, h, l);
      hi8[j] = (short)h;
      lo8[j] = (short)l;
    }
    int off = r * 512 + ((ch0 * 2) ^ ((r & 7) << 4));
    *(short8*)((char*)Ah_s + off) = hi8;
    *(short8*)((char*)Al_s + off) = lo8;
  }
  __syncthreads();

  // phase 2: k-loop. wave -> 64 combined cols (mat = L if combc<N else R).
  const int wave = tid >> 6, lane = tid & 63;
  const int cn = lane & 15, kgrp = lane >> 4;
  const int combc = wave * 64;
  const bool isR = combc >= N;
  const ushort* Bh = BT + (isR ? 2 * PLANE : 0);
  const ushort* Bl_ = Bh + PLANE;
  const int cb = combc & (N - 1);
  f32x4 acc[4][4];
  #pragma unroll
  for (int rt = 0; rt < 4; ++rt)
    #pragma unroll
    for (int ct = 0; ct < 4; ++ct) acc[rt][ct] = (f32x4)(0.f);

  #pragma unroll 2
  for (int k0 = 0; k0 < 256; k0 += 32) {
    short8 ah[4], al[4];
    #pragma unroll
    for (int rt = 0; rt < 4; ++rt) {
      int row = rt * 16 + cn;
      int off = row * 512 + (((k0 * 2) + kgrp * 16) ^ ((row & 7) << 4));
      ah[rt] = *(const short8*)((const char*)Ah_s + off);
      al[rt] = *(const short8*)((const char*)Al_s + off);
    }
    const size_t bbase = (size_t)((k0 >> 3) + kgrp) * (N * 8);
    #pragma unroll
    for (int ct = 0; ct < 4; ++ct) {
      const size_t bo = bbase + (size_t)(cb + ct * 16 + cn) * 8;
      short8 bh = *(const short8*)&Bh[bo];
      short8 bl = *(const short8*)&Bl_[bo];
      #pragma unroll
      for (int rt = 0; rt < 4; ++rt) {
        acc[rt][ct] = __builtin_amdgcn_mfma_f32_16x16x32_bf16(ah[rt], bh, acc[rt][ct], 0, 0, 0);
        acc[rt][ct] = __builtin_amdgcn_mfma_f32_16x16x32_bf16(ah[rt], bl, acc[rt][ct], 0, 0, 0);
        acc[rt][ct] = __builtin_amdgcn_mfma_f32_16x16x32_bf16(al[rt], bh, acc[rt][ct], 0, 0, 0);
      }
    }
  }

  // epilogue: C/D layout col=lane&15, row=(lane>>4)*4+reg  [m89 verified]
  #pragma unroll
  for (int ct = 0; ct < 4; ++ct) {
    int cc = cb + ct * 16 + cn;
    #pragma unroll
    for (int rt = 0; rt < 4; ++rt) {
      int crow0 = brow0 + rt * 16 + kgrp * 4;
      #pragma unroll
      for (int j = 0; j < 4; ++j) {
        int rr = crow0 + j;
        if (rr < N_NODES) {
          if (!isR) Clb[(size_t)rr * N + cc] = f2bf(acc[rt][ct][j]);
          else      Cr[(size_t)rr * N + cc] = acc[rt][ct][j];
        }
      }
    }
  }
}

// ---------------- CSR build: histogram -> multi-block scan -> scatter
__global__ void hist_kernel(const int* __restrict__ dsts, int* __restrict__ curs) {
  int i = blockIdx.x * blockDim.x + threadIdx.x;
  if (i >= ET) return;
  int d = (i < N_EDGES) ? dsts[i] : i - N_EDGES;
  atomicAdd(&curs[d], 1);
}

__global__ __launch_bounds__(256) void scan_part(
    const int* __restrict__ curs, int* __restrict__ rows, int* __restrict__ bsum)
{
  __shared__ int tmp[256];
  int t = threadIdx.x;
  int i = blockIdx.x * 256 + t;
  int v = (i < N_NODES) ? curs[i] : 0;
  tmp[t] = v;
  __syncthreads();
  #pragma unroll
  for (int off = 1; off < 256; off <<= 1) {
    int u = (t >= off) ? tmp[t - off] : 0;
    __syncthreads();
    tmp[t] += u;
    __syncthreads();
  }
  if (i < N_NODES) rows[i] = tmp[t] - v;
  if (t == 255) bsum[blockIdx.x] = tmp[255];
}

__global__ __launch_bounds__(256) void scan_bsums(
    const int* __restrict__ bsum, int* __restrict__ boff)
{
  __shared__ int tmp[256];
  int t = threadIdx.x;
  int v = (t < SCAN_BLOCKS) ? bsum[t] : 0;
  tmp[t] = v;
  __syncthreads();
  #pragma unroll
  for (int off = 1; off < 256; off <<= 1) {
    int u = (t >= off) ? tmp[t - off] : 0;
    __syncthreads();
    tmp[t] += u;
    __syncthreads();
  }
  if (t < SCAN_BLOCKS) boff[t] = tmp[t] - v;
}

__global__ __launch_bounds__(256) void scan_apply(
    int* __restrict__ rows, const int* __restrict__ boff, int* __restrict__ curs)
{
  int i = blockIdx.x * 256 + threadIdx.x;
  if (i < N_NODES) {
    int r = rows[i] + boff[blockIdx.x];
    rows[i] = r;
    curs[i] = r;
  }
  if (i == 0) rows[N_NODES] = ET;
}

__global__ void scatter_kernel(const int* __restrict__ srcs, const int* __restrict__ dsts,
                               int* __restrict__ curs, int* __restrict__ esrc) {
  int i = blockIdx.x * blockDim.x + threadIdx.x;
  if (i >= ET) return;
  int s, d;
  if (i < N_EDGES) { s = srcs[i]; d = dsts[i]; } else { s = d = i - N_EDGES; }
  int pos = atomicAdd(&curs[d], 1);
  esrc[pos] = s;
}

// ---------------- fused flash-attention pass: one wave per dst, online softmax,
// bf16 xl gathers, fp32 xr, 4 edges/iter (D=256), register accumulator.
template<int HEADS_, int D_>
__global__ __launch_bounds__(256) void flash_csr(
    const ushort* __restrict__ xl, const float* __restrict__ xr,
    const float* __restrict__ att, const int* __restrict__ rows,
    const int* __restrict__ esrc, float* __restrict__ out)
{
  int d = blockIdx.x * 4 + (threadIdx.x >> 6);
  if (d >= N_NODES) return;
  int lane = threadIdx.x & 63;
  int beg = rows[d], end = rows[d + 1];
  if constexpr (D_ == 256) {
    float4 xrv = *(const float4*)&xr[(size_t)d * 256 + lane * 4];
    float4 w = *(const float4*)&att[lane * 4];
    auto score = [&](float b0, float b1, float b2, float b3) {
      float v0 = b0 + xrv.x, v1 = b1 + xrv.y, v2 = b2 + xrv.z, v3 = b3 + xrv.w;
      v0 = v0 > 0.f ? v0 : 0.2f * v0;
      v1 = v1 > 0.f ? v1 : 0.2f * v1;
      v2 = v2 > 0.f ? v2 : 0.2f * v2;
      v3 = v3 > 0.f ? v3 : 0.2f * v3;
      return fmaf(v0, w.x, fmaf(v1, w.y, fmaf(v2, w.z, v3 * w.w)));
    };
    float m = -INFINITY, s = 0.f;
    float a0 = 0.f, a1 = 0.f, a2 = 0.f, a3 = 0.f;
    int p = beg;
    for (; p + 4 <= end; p += 4) {
      int s1 = esrc[p], s2 = esrc[p + 1], s3 = esrc[p + 2], s4 = esrc[p + 3];
      ushort4 u1 = *(const ushort4*)&xl[(size_t)s1 * 256 + lane * 4];
      ushort4 u2 = *(const ushort4*)&xl[(size_t)s2 * 256 + lane * 4];
      ushort4 u3 = *(const ushort4*)&xl[(size_t)s3 * 256 + lane * 4];
      ushort4 u4 = *(const ushort4*)&xl[(size_t)s4 * 256 + lane * 4];
      float b10 = bf2f(u1.x), b11 = bf2f(u1.y), b12 = bf2f(u1.z), b13 = bf2f(u1.w);
      float b20 = bf2f(u2.x), b21 = bf2f(u2.y), b22 = bf2f(u2.z), b23 = bf2f(u2.w);
      float b30 = bf2f(u3.x), b31 = bf2f(u3.y), b32 = bf2f(u3.z), b33 = bf2f(u3.w);
      float b40 = bf2f(u4.x), b41 = bf2f(u4.y), b42 = bf2f(u4.z), b43 = bf2f(u4.w);
      float e1 = score(b10, b11, b12, b13);
      float e2 = score(b20, b21, b22, b23);
      float e3 = score(b30, b31, b32, b33);
      float e4 = score(b40, b41, b42, b43);
      e1 += __shfl_xor(e1, 1); e2 += __shfl_xor(e2, 1);
      e3 += __shfl_xor(e3, 1); e4 += __shfl_xor(e4, 1);
      e1 += __shfl_xor(e1, 2); e2 += __shfl_xor(e2, 2);
      e3 += __shfl_xor(e3, 2); e4 += __shfl_xor(e4, 2);
      e1 += __shfl_xor(e1, 4); e2 += __shfl_xor(e2, 4);
      e3 += __shfl_xor(e3, 4); e4 += __shfl_xor(e4, 4);
      e1 += __shfl_xor(e1, 8); e2 += __shfl_xor(e2, 8);
      e3 += __shfl_xor(e3, 8); e4 += __shfl_xor(e4, 8);
      float mn = fmaxf(fmaxf(m, fmaxf(e1, e2)), fmaxf(e3, e4));
      float f = __expf(m - mn);
      float p1 = __expf(e1 - mn);
      float p2 = __expf(e2 - mn);
      float p3 = __expf(e3 - mn);
      float p4 = __expf(e4 - mn);
      s = fmaf(s, f, (p1 + p2) + (p3 + p4));
      a0 = fmaf(a0, f, fmaf(p1, b10, fmaf(p2, b20, fmaf(p3, b30, p4 * b40))));
      a1 = fmaf(a1, f, fmaf(p1, b11, fmaf(p2, b21, fmaf(p3, b31, p4 * b41))));
      a2 = fmaf(a2, f, fmaf(p1, b12, fmaf(p2, b22, fmaf(p3, b32, p4 * b42))));
      a3 = fmaf(a3, f, fmaf(p1, b13, fmaf(p2, b23, fmaf(p3, b33, p4 * b43))));
      m = mn;
    }
    for (; p < end; ++p) {
      int s1 = esrc[p];
      ushort4 u1 = *(const ushort4*)&xl[(size_t)s1 * 256 + lane * 4];
      float b10 = bf2f(u1.x), b11 = bf2f(u1.y), b12 = bf2f(u1.z), b13 = bf2f(u1.w);
      float e1 = score(b10, b11, b12, b13);
      e1 += __shfl_xor(e1, 1);
      e1 += __shfl_xor(e1, 2);
      e1 += __shfl_xor(e1, 4);
      e1 += __shfl_xor(e1, 8);
      float mn = fmaxf(m, e1);
      float f = __expf(m - mn);
      float p1 = __expf(e1 - mn);
      s = fmaf(s, f, p1);
      a0 = fmaf(a0, f, p1 * b10);
      a1 = fmaf(a1, f, p1 * b11);
      a2 = fmaf(a2, f, p1 * b12);
      a3 = fmaf(a3, f, p1 * b13);
      m = mn;
    }
    float inv = 1.f / (s + 1e-16f);
    *(float4*)&out[(size_t)d * 256 + lane * 4] =
        make_float4(a0 * inv, a1 * inv, a2 * inv, a3 * inv);
  } else {  // 1 head, D=64
    float xrv = xr[(size_t)d * 64 + lane];
    float w = att[lane];
    float m = -INFINITY, s = 0.f, acc = 0.f;
    int p = beg;
    for (; p + 2 <= end; p += 2) {
      int s1 = esrc[p], s2 = esrc[p + 1];
      float b1 = bf2f(xl[(size_t)s1 * 64 + lane]);
      float b2 = bf2f(xl[(size_t)s2 * 64 + lane]);
      float v1 = b1 + xrv, v2 = b2 + xrv;
      v1 = v1 > 0.f ? v1 : 0.2f * v1;
      v2 = v2 > 0.f ? v2 : 0.2f * v2;
      float e1 = v1 * w, e2 = v2 * w;
      e1 += __shfl_xor(e1, 1);  e2 += __shfl_xor(e2, 1);
      e1 += __shfl_xor(e1, 2);  e2 += __shfl_xor(e2, 2);
      e1 += __shfl_xor(e1, 4);  e2 += __shfl_xor(e2, 4);
      e1 += __shfl_xor(e1, 8);  e2 += __shfl_xor(e2, 8);
      e1 += __shfl_xor(e1, 16); e2 += __shfl_xor(e2, 16);
      e1 += __shfl_xor(e1, 32); e2 += __shfl_xor(e2, 32);
      float mn = fmaxf(m, fmaxf(e1, e2));
      float f = __expf(m - mn);
      float p1 = __expf(e1 - mn);
      float p2 = __expf(e2 - mn);
      s = fmaf(s, f, p1 + p2);
      acc = fmaf(acc, f, fmaf(p1, b1, p2 * b2));
      m = mn;
    }
    if (p < end) {
      int s1 = esrc[p];
      float b1 = bf2f(xl[(size_t)s1 * 64 + lane]);
      float v1 = b1 + xrv;
      v1 = v1 > 0.f ? v1 : 0.2f * v1;
      float e1 = v1 * w;
      e1 += __shfl_xor(e1, 1);
      e1 += __shfl_xor(e1, 2);
      e1 += __shfl_xor(e1, 4);
      e1 += __shfl_xor(e1, 8);
      e1 += __shfl_xor(e1, 16);
      e1 += __shfl_xor(e1, 32);
      float mn = fmaxf(m, e1);
      float f = __expf(m - mn);
      float p1 = __expf(e1 - mn);
      s = fmaf(s, f, p1);
      acc = fmaf(acc, f, p1 * b1);
    }
    out[(size_t)d * 64 + lane] = acc / (s + 1e-16f);
  }
}

// ---------------- BN statistics (per-channel sum / sumsq)
template<int D_, int RPB>
__global__ __launch_bounds__(256) void bn_stats(const float* __restrict__ h,
    float* __restrict__ gsum, float* __restrict__ gsumsq, int nrows)
{
  constexpr int RG = 256 / D_;
  int c = threadIdx.x % D_;
  int rg = threadIdx.x / D_;
  int r0 = blockIdx.x * RPB;
  float s = 0.f, sq = 0.f;
  int rend = min(r0 + RPB, nrows);
  for (int r = r0 + rg; r < rend; r += RG) {
    float v = h[(size_t)r * D_ + c];
    s += v;
    sq = fmaf(v, v, sq);
  }
  atomicAdd(&gsum[c], s);
  atomicAdd(&gsumsq[c], sq);
}

// ---------------- fused pooling (BN finalize+apply inline) + classifier MLP.
__global__ __launch_bounds__(256) void pool_mlp(
    const float* __restrict__ h3, const int* __restrict__ batch,
    const float* __restrict__ gsum, const float* __restrict__ gsumsq,
    const float* __restrict__ g3, const float* __restrict__ be3,
    const float* __restrict__ Wc1, const float* __restrict__ bc1,
    const float* __restrict__ Wc2, const float* __restrict__ bc2,
    float* __restrict__ outp)
{
  int g = blockIdx.x;
  int t = threadIdx.x;
  int lane = t & 63, w = t >> 6;
  int lo, hi;
  {
    int a = 0, b = N_NODES;
    while (a < b) { int mid = (a + b) >> 1; if (batch[mid] < g) a = mid + 1; else b = mid; }
    lo = a;
    b = N_NODES;
    while (a < b) { int mid = (a + b) >> 1; if (batch[mid] < g + 1) a = mid + 1; else b = mid; }
    hi = a;
  }
  const float invn = 1.0f / (float)N_NODES;
  float mu = gsum[lane] * invn;
  float var = gsumsq[lane] * invn - mu * mu;
  float scl = g3[lane] * rsqrtf(var + 1e-5f);
  float shf = be3[lane] - mu * scl;
  float s = 0.f, mx = -INFINITY;
  for (int r = lo + w; r < hi; r += 4) {
    float v = fmaf(h3[(size_t)r * 64 + lane], scl, shf);
    s += v;
    mx = fmaxf(mx, v);
  }
  __shared__ float ssum[4][64];
  __shared__ float smax[4][64];
  __shared__ float pooled[128];
  ssum[w][lane] = s;
  smax[w][lane] = mx;
  __syncthreads();
  if (w == 0) {
    float tot = ssum[0][lane] + ssum[1][lane] + ssum[2][lane] + ssum[3][lane];
    float m4 = fmaxf(fmaxf(smax[0][lane], smax[1][lane]),
                     fmaxf(smax[2][lane], smax[3][lane]));
    float cnt = (float)(hi - lo);
    pooled[lane] = tot / fmaxf(cnt, 1.f);
    pooled[64 + lane] = m4;
  }
  __syncthreads();
  if (w == 0) {
    float a = bc1[lane];
    #pragma unroll 8
    for (int k = 0; k < 128; ++k) a = fmaf(pooled[k], Wc1[k * 64 + lane], a);
    a = fmaxf(a, 0.f);
    float v = a * Wc2[lane];
    v += __shfl_xor(v, 1);
    v += __shfl_xor(v, 2);
    v += __shfl_xor(v, 4);
    v += __shfl_xor(v, 8);
    v += __shfl_xor(v, 16);
    v += __shfl_xor(v, 32);
    if (lane == 0) outp[g] = v + bc2[0];
  }
}

extern "C" void kernel_launch(void* const* d_in, const int* in_sizes, int n_in,
                              void* d_out, int out_size, void* d_ws, size_t ws_size,
                              hipStream_t stream)
{
  const float* x    = (const float*)d_in[0];
  const int*   ei   = (const int*)d_in[1];
  const int*   batch= (const int*)d_in[2];
  const float* Wl1  = (const float*)d_in[3];
  const float* Wr1  = (const float*)d_in[4];
  const float* att1 = (const float*)d_in[5];
  // b1/b2/b3 cancel in the following BatchNorm -> unused
  const float* g1   = (const float*)d_in[7];
  const float* be1  = (const float*)d_in[8];
  const float* Wl2  = (const float*)d_in[9];
  const float* Wr2  = (const float*)d_in[10];
  const float* att2 = (const float*)d_in[11];
  const float* g2   = (const float*)d_in[13];
  const float* be2  = (const float*)d_in[14];
  const float* Wl3  = (const float*)d_in[15];
  const float* Wr3  = (const float*)d_in[16];
  const float* att3 = (const float*)d_in[17];
  const float* g3   = (const float*)d_in[19];
  const float* be3  = (const float*)d_in[20];
  const float* Wc1  = (const float*)d_in[21];
  const float* bc1  = (const float*)d_in[22];
  const float* Wc2  = (const float*)d_in[23];
  const float* bc2  = (const float*)d_in[24];

  const int* srcs = ei;
  const int* dsts = ei + N_EDGES;

  float* ws = (float*)d_ws;
  size_t o = 0;
  ushort* XLB = (ushort*)(ws + o); o += (size_t)N_NODES * HIDD / 2;  // bf16 xl
  float* XR = ws + o;            o += (size_t)N_NODES * HIDD;
  float* Hb = ws + o;            o += (size_t)N_NODES * HIDD;
  ushort* BT2 = (ushort*)(ws + o); o += (size_t)4 * 32 * 256 * 8 / 2;   // 2 mats x 2 halves
  ushort* BT3 = (ushort*)(ws + o); o += (size_t)4 * 32 * 64 * 8 / 2;
  int* ESRC = (int*)(ws + o);    o += ET;
  int* ROWS = (int*)(ws + o);    o += N_NODES + 1;
  int* CURS = (int*)(ws + o);    o += N_NODES;
  int* BSUM = (int*)(ws + o);    o += SCAN_BLOCKS;
  int* BOFF = (int*)(ws + o);    o += SCAN_BLOCKS;
  float* GS  = ws + o;           o += 256;
  float* GSQ = ws + o;           o += 256;

  const int ROW_BLOCKS = (N_NODES + 63) / 64;
  const int DST_BLOCKS = (N_NODES + 3) / 4;
  constexpr int PLANE2 = 32 * 256 * 8;
  constexpr int PLANE3 = 32 * 64 * 8;

  // ================= weight transpose/split (independent; run once up front)
  convertB<256, 256><<<(65536 + 255) / 256, 256, 0, stream>>>(Wl2, BT2);
  convertB<256, 256><<<(65536 + 255) / 256, 256, 0, stream>>>(Wr2, BT2 + 2 * PLANE2);
  convertB<256, 64><<<(16384 + 255) / 256, 256, 0, stream>>>(Wl3, BT3);
  convertB<256, 64><<<(16384 + 255) / 256, 256, 0, stream>>>(Wr3, BT3 + 2 * PLANE3);

  // ================= CSR build (reused by all 3 layers) =================
  hipMemsetAsync(CURS, 0, N_NODES * 4, stream);
  hist_kernel<<<(ET + 255) / 256, 256, 0, stream>>>(dsts, CURS);
  scan_part<<<SCAN_BLOCKS, 256, 0, stream>>>(CURS, ROWS, BSUM);
  scan_bsums<<<1, 256, 0, stream>>>(BSUM, BOFF);
  scan_apply<<<SCAN_BLOCKS, 256, 0, stream>>>(ROWS, BOFF, CURS);
  scatter_kernel<<<(ET + 255) / 256, 256, 0, stream>>>(srcs, dsts, CURS, ESRC);

  // ================= layer 1 (16 -> 4x64, concat): fp32 vector GEMM ======
  gemm_dual<16, 256><<<dim3(ROW_BLOCKS, 4), 256, 0, stream>>>(
      x, Wl1, Wr1, XLB, XR, N_NODES);
  flash_csr<4, 256><<<DST_BLOCKS, 256, 0, stream>>>(XLB, XR, att1, ROWS, ESRC, Hb);
  hipMemsetAsync(GS, 0, 512 * 4, stream);
  bn_stats<256, 64><<<ROW_BLOCKS, 256, 0, stream>>>(Hb, GS, GSQ, N_NODES);

  // ================= layer 2 (256 -> 4x64): fully-fused BN+ELU+MFMA GEMM ==
  gemm_fused<256><<<ROW_BLOCKS, 512, 0, stream>>>(
      Hb, GS, GSQ, g1, be1, BT2, XLB, XR);
  flash_csr<4, 256><<<DST_BLOCKS, 256, 0, stream>>>(XLB, XR, att2, ROWS, ESRC, Hb);
  hipMemsetAsync(GS, 0, 512 * 4, stream);
  bn_stats<256, 64><<<ROW_BLOCKS, 256, 0, stream>>>(Hb, GS, GSQ, N_NODES);

  // ================= layer 3 (256 -> 64, 1 head): fused MFMA GEMM ========
  gemm_fused<64><<<ROW_BLOCKS, 128, 0, stream>>>(
      Hb, GS, GSQ, g2, be2, BT3, XLB, XR);
  flash_csr<1, 64><<<DST_BLOCKS, 256, 0, stream>>>(XLB, XR, att3, ROWS, ESRC, Hb);
  hipMemsetAsync(GS, 0, 512 * 4, stream);
  bn_stats<64, 256><<<(N_NODES + 255) / 256, 256, 0, stream>>>(Hb, GS, GSQ, N_NODES);

  // ================= fused pooling (BN inline) + classifier ==============
  pool_mlp<<<N_GRAPHS, 256, 0, stream>>>(Hb, batch, GS, GSQ, g3, be3,
                                         Wc1, bc1, Wc2, bc2, (float*)d_out);
}